// Round 3
// baseline (300.554 us; speedup 1.0000x reference)
//
#include <hip/hip_runtime.h>
#include <math.h>

#define NS 4
#define NC 128
#define HH 64
#define WW 64
#define LL 1024   // 32*32

typedef unsigned short u16;
typedef u16 u16x4 __attribute__((ext_vector_type(4)));
typedef short s16x8 __attribute__((ext_vector_type(8)));
typedef float f32x4 __attribute__((ext_vector_type(4)));

__device__ __forceinline__ u16 f2bf(float x) {
  unsigned u = __float_as_uint(x);
  return (u16)((u + 0x7FFFu + ((u >> 16) & 1u)) >> 16);
}
__device__ __forceinline__ float bf2f(u16 h) {
  return __uint_as_float(((unsigned)h) << 16);
}

// ---------------- prep: transposed hi/lo bf16 operands for gram
// bsT/fsT[(s*LL + row)*NC + c] : row-major, c contiguous
__global__ __launch_bounds__(256) void prep_T(const float* __restrict__ f,
                                              const float* __restrict__ b,
                                              u16* __restrict__ bsT_hi, u16* __restrict__ bsT_lo,
                                              u16* __restrict__ fsT_hi, u16* __restrict__ fsT_lo) {
  int idx = blockIdx.x * 256 + threadIdx.x;      // 4*1024*16 = 65536
  int co = (idx & 15) * 8;
  int q  = (idx >> 4) & 1023;
  int s  = idx >> 14;
  int qh = q >> 5, qw = q & 31;
  size_t g0 = ((size_t)(s * NC) * HH + 2 * qh) * WW + 2 * qw;
  u16x4 fh0, fh1, fl0, fl1, bh0, bh1, bl0, bl1;
  u16* fhv[2] = { (u16*)&fh0, (u16*)&fh1 };
  u16* flv[2] = { (u16*)&fl0, (u16*)&fl1 };
  u16* bhv[2] = { (u16*)&bh0, (u16*)&bh1 };
  u16* blv[2] = { (u16*)&bl0, (u16*)&bl1 };
#pragma unroll
  for (int e = 0; e < 8; ++e) {
    size_t off = g0 + (size_t)(co + e) * (HH * WW);
    float xf = f[off], xb = b[off];
    u16 hf = f2bf(xf); u16 lf = f2bf(xf - bf2f(hf));
    u16 hb = f2bf(xb); u16 lb = f2bf(xb - bf2f(hb));
    fhv[e >> 2][e & 3] = hf; flv[e >> 2][e & 3] = lf;
    bhv[e >> 2][e & 3] = hb; blv[e >> 2][e & 3] = lb;
  }
  size_t o = ((size_t)(s * LL) + q) * NC + co;
  *(u16x4*)(fsT_hi + o) = fh0; *(u16x4*)(fsT_hi + o + 4) = fh1;
  *(u16x4*)(fsT_lo + o) = fl0; *(u16x4*)(fsT_lo + o + 4) = fl1;
  *(u16x4*)(bsT_hi + o) = bh0; *(u16x4*)(bsT_hi + o + 4) = bh1;
  *(u16x4*)(bsT_lo + o) = bl0; *(u16x4*)(bsT_lo + o + 4) = bl1;
}

// ---------------- prep: Wt[z][c][k] bf16 = b[s][c][2kh+py][2kw+px], k = kh*32+kw
__global__ __launch_bounds__(256) void prep_wt(const float* __restrict__ b,
                                               u16* __restrict__ Wt) {
  int q = blockIdx.x * 256 + threadIdx.x;        // 524288 quads
  int k4 = (q & 255) * 4;
  int c  = (q >> 8) & 127;
  int z  = q >> 15;
  int s = z >> 2, cls = z & 3, py = cls >> 1, px = cls & 1;
  int kh = k4 >> 5, kw = k4 & 31;
  const float* src = b + ((size_t)(s * NC + c) * HH + 2 * kh + py) * WW + px;
  u16x4 v;
#pragma unroll
  for (int i = 0; i < 4; ++i) v[i] = f2bf(src[2 * (kw + i)]);
  *(u16x4*)(Wt + (size_t)q * 4) = v;
}

// ---------------- gram via split-bf16 MFMA: G[s][p][q] = sum_c bs[c][p]*fs[c][q]
// one wave per block: 1 m-tile (16 p) x 2 n-tiles (32 q), K=128
__global__ __launch_bounds__(64) void gram_mfma(const u16* __restrict__ bsT_hi,
                                                const u16* __restrict__ bsT_lo,
                                                const u16* __restrict__ fsT_hi,
                                                const u16* __restrict__ fsT_lo,
                                                float* __restrict__ G) {
  int wid = blockIdx.x;                 // 8192 = 4s * 64mt * 32ng
  int ng = wid & 31, mt = (wid >> 5) & 63, s = wid >> 11;
  int l = threadIdx.x, lr = l & 15, lg = l >> 4;
  size_t ab  = ((size_t)(s * LL) + mt * 16 + lr) * NC + lg * 8;
  size_t b0b = ((size_t)(s * LL) + ng * 32 + lr) * NC + lg * 8;
  size_t b1b = b0b + (size_t)16 * NC;
  f32x4 acc0 = {}, acc1 = {};
#pragma unroll
  for (int kc = 0; kc < 4; ++kc) {
    int o = kc * 32;
    s16x8 ah  = *(const s16x8*)(bsT_hi + ab + o);
    s16x8 al  = *(const s16x8*)(bsT_lo + ab + o);
    s16x8 bh0 = *(const s16x8*)(fsT_hi + b0b + o);
    s16x8 bl0 = *(const s16x8*)(fsT_lo + b0b + o);
    s16x8 bh1 = *(const s16x8*)(fsT_hi + b1b + o);
    s16x8 bl1 = *(const s16x8*)(fsT_lo + b1b + o);
    acc0 = __builtin_amdgcn_mfma_f32_16x16x32_bf16(ah, bh0, acc0, 0, 0, 0);
    acc0 = __builtin_amdgcn_mfma_f32_16x16x32_bf16(ah, bl0, acc0, 0, 0, 0);
    acc0 = __builtin_amdgcn_mfma_f32_16x16x32_bf16(al, bh0, acc0, 0, 0, 0);
    acc1 = __builtin_amdgcn_mfma_f32_16x16x32_bf16(ah, bh1, acc1, 0, 0, 0);
    acc1 = __builtin_amdgcn_mfma_f32_16x16x32_bf16(ah, bl1, acc1, 0, 0, 0);
    acc1 = __builtin_amdgcn_mfma_f32_16x16x32_bf16(al, bh1, acc1, 0, 0, 0);
  }
  float* Gs = G + ((size_t)s << 20);
  int prow = mt * 16 + lg * 4;
  int q0 = ng * 32 + lr;
#pragma unroll
  for (int r = 0; r < 4; ++r) {
    Gs[(size_t)(prow + r) * LL + q0]      = acc0[r];
    Gs[(size_t)(prow + r) * LL + q0 + 16] = acc1[r];
  }
}

// ---------------- norms (patch L2 incl. +1e-4 per element) and mask means
__global__ __launch_bounds__(1024) void norm_mm(const u16* __restrict__ bsT_hi,
                                                const u16* __restrict__ bsT_lo,
                                                const float* __restrict__ mask,
                                                float* __restrict__ nrm,
                                                float* __restrict__ mmv) {
  int s = blockIdx.x;
  int p = threadIdx.x;             // 1024
  __shared__ float Q[LL];
  __shared__ float M[LL];
  const u16* hb = bsT_hi + ((size_t)(s * LL) + p) * NC;
  const u16* lb = bsT_lo + ((size_t)(s * LL) + p) * NC;
  float q = 0.f;
  for (int co = 0; co < NC; co += 8) {
    s16x8 h = *(const s16x8*)(hb + co);
    s16x8 lo = *(const s16x8*)(lb + co);
#pragma unroll
    for (int e = 0; e < 8; ++e) {
      float v = bf2f((u16)h[e]) + bf2f((u16)lo[e]);
      q += v * v;
    }
  }
  Q[p] = q;
  int ph = p >> 5, pw = p & 31;
  M[p] = mask[s * HH * WW + (2 * ph) * WW + 2 * pw];
  __syncthreads();
  float sum2 = 1152 * 1e-4f;       // sum of the +0.0001 terms (128*3*3)
  float msum = 0.f;
#pragma unroll
  for (int dh = -1; dh <= 1; ++dh)
#pragma unroll
    for (int dw = -1; dw <= 1; ++dw) {
      int h = ph + dh, w = pw + dw;
      if (h >= 0 && h < 32 && w >= 0 && w < 32) {
        sum2 += Q[h * 32 + w];
        msum += M[h * 32 + w];
      }
    }
  nrm[s * LL + p] = sqrtf(sum2);
  mmv[s * LL + p] = msum * (1.f / 9.f);
}

// ---------------- S[p][q] = (sum of 9 diagonal 2D taps of G) / norm[p]
__global__ __launch_bounds__(256) void sbuild(const float* __restrict__ G,
                                              const float* __restrict__ nrm,
                                              float* __restrict__ S) {
  int s = blockIdx.z;
  int p = blockIdx.y;
  int q = blockIdx.x * 256 + threadIdx.x;
  int ph = p >> 5, pw = p & 31, qh = q >> 5, qw = q & 31;
  const float* Gs = G + (size_t)s * LL * LL;
  float acc = 0.f;
#pragma unroll
  for (int dh = -1; dh <= 1; ++dh)
#pragma unroll
    for (int dw = -1; dw <= 1; ++dw) {
      int ph2 = ph + dh, pw2 = pw + dw, qh2 = qh + dh, qw2 = qw + dw;
      if (ph2 >= 0 && ph2 < 32 && pw2 >= 0 && pw2 < 32 &&
          qh2 >= 0 && qh2 < 32 && qw2 >= 0 && qw2 < 32)
        acc += Gs[(size_t)(ph2 * 32 + pw2) * LL + qh2 * 32 + qw2];
    }
  S[(size_t)s * LL * LL + (size_t)p * LL + q] = acc / nrm[s * LL + p];
}

// ---------------- fuse pass 1: flat diagonal 3-tap in (I,J)
__global__ __launch_bounds__(256) void fuse1(const float* __restrict__ S,
                                             float* __restrict__ F1) {
  int s = blockIdx.z;
  int I = blockIdx.y;
  int J = blockIdx.x * 256 + threadIdx.x;
  const float* Ss = S + (size_t)s * LL * LL;
  float v = Ss[(size_t)I * LL + J];
  if (I > 0 && J > 0)           v += Ss[(size_t)(I - 1) * LL + J - 1];
  if (I < LL - 1 && J < LL - 1) v += Ss[(size_t)(I + 1) * LL + J + 1];
  F1[(size_t)s * LL * LL + (size_t)I * LL + J] = v;
}

// ---------------- fuse pass 2: diagonal 3-tap in transposed flattening
__global__ __launch_bounds__(256) void fuse2(const float* __restrict__ F1,
                                             float* __restrict__ F2) {
  int s = blockIdx.z;
  int I = blockIdx.y;                        // ibh*32+ibw
  int J = blockIdx.x * 256 + threadIdx.x;    // fhi*32+fwi
  int ibh = I >> 5, ibw = I & 31, fhi = J >> 5, fwi = J & 31;
  int Ip = ibw * 32 + ibh, Jp = fwi * 32 + fhi;
  const float* F = F1 + (size_t)s * LL * LL;
  float v = 0.f;
#pragma unroll
  for (int d = -1; d <= 1; ++d) {
    int a = Ip + d, bb = Jp + d;
    if (a >= 0 && a < LL && bb >= 0 && bb < LL) {
      int I2 = (a & 31) * 32 + (a >> 5);
      int J2 = (bb & 31) * 32 + (bb >> 5);
      v += F[(size_t)I2 * LL + J2];
    }
  }
  F2[(size_t)s * LL * LL + (size_t)I * LL + J] = v;
}

// ---------------- column softmax over p (with mm applied pre/post), write transposed yiT[q][p]
__global__ __launch_bounds__(256) void softmax_k(const float* __restrict__ F2,
                                                 const float* __restrict__ mmv,
                                                 float* __restrict__ yiT) {
  int s  = blockIdx.y;
  int q0 = blockIdx.x * 16;
  int t  = threadIdx.x;
  int qx = t & 15, pg = t >> 4;
  const float* F  = F2 + (size_t)s * LL * LL;
  const float* mm = mmv + s * LL;
  __shared__ float red[16][17];
  float mx = -1e30f;
  for (int j = 0; j < 64; ++j) {
    int p = pg + 16 * j;
    float v = F[(size_t)p * LL + q0 + qx] * mm[p] * 10.f;
    mx = fmaxf(mx, v);
  }
  red[pg][qx] = mx;
  __syncthreads();
  float m = -1e30f;
  for (int i = 0; i < 16; ++i) m = fmaxf(m, red[i][qx]);
  __syncthreads();
  float sm = 0.f;
  for (int j = 0; j < 64; ++j) {
    int p = pg + 16 * j;
    float v = F[(size_t)p * LL + q0 + qx] * mm[p] * 10.f;
    sm += __expf(v - m);
  }
  red[pg][qx] = sm;
  __syncthreads();
  float tot = 0.f;
  for (int i = 0; i < 16; ++i) tot += red[i][qx];
  float inv = 1.f / tot;
  float* yo = yiT + (size_t)s * LL * LL + (size_t)(q0 + qx) * LL;
  for (int j = 0; j < 64; ++j) {
    int p = pg * 64 + j;
    float v = F[(size_t)p * LL + q0 + qx] * mm[p] * 10.f;
    yo[p] = __expf(v - m) * inv * mm[p];
  }
}

// ---------------- build P matrix (4-tap diagonal sums of yiT) as bf16, k-contiguous
// Pb[((zg*LL + n)*LL + k], zg = z - zbase, 8 z per batch (16 MB)
__global__ __launch_bounds__(256) void build_p(const float* __restrict__ yiT,
                                               u16* __restrict__ Pb, int zbase) {
  int idx = blockIdx.x * 256 + threadIdx.x;      // 8*1024*128 = 1048576
  int koct = idx & 127;  int k0 = koct * 8;
  int n  = (idx >> 7) & 1023;
  int zg = idx >> 17;
  int z  = zbase + zg;
  int s = z >> 2, cls = z & 3;
  int py = cls >> 1, px = cls & 1;
  int sy = py ? 1 : -1, sx = px ? 1 : -1;
  const float* Y = yiT + ((size_t)s << 20);
  int ih = n >> 5, jw = n & 31, kh = k0 >> 5, kwb = k0 & 31;
  int dy = sy * (32 * LL + 32);
  int dx = sx * (LL + 1);
  bool vy  = ((unsigned)(ih + sy) < 32u) && ((unsigned)(kh + sy) < 32u);
  bool vxr = ((unsigned)(jw + sx) < 32u);
  const float* base = Y + (size_t)n * LL + k0;
  s16x8 pk;
#pragma unroll
  for (int e = 0; e < 8; ++e) {
    float a  = base[e];
    float bv = vy ? base[e + dy] : 0.f;
    bool vx  = vxr && ((unsigned)(kwb + e + sx) < 32u);
    float cv = vx ? base[e + dx] : 0.f;
    float dv = (vx && vy) ? base[e + dx + dy] : 0.f;
    pk[e] = (short)f2bf((a + bv) + (cv + dv));
  }
  *(s16x8*)(Pb + (((size_t)(zg * LL + n)) << 10) + k0) = pk;
}

// ---------------- deconv GEMM, barrier-free, 1 wave/block:
// out[c][n'] = 0.25 * sum_k Wt[z][c][k] * Pb[zg][n][k]
// per wave: 1 m-tile (16 c) x 2 n-tiles (32 n), K=1024
__global__ __launch_bounds__(64) void deconv_gemm(const u16* __restrict__ Pb,
                                                  const u16* __restrict__ Wt,
                                                  float* __restrict__ out, int zbase) {
  int wid = blockIdx.x;                 // 2048 = 8zg * 8mt * 32ng
  int ng = wid & 31, mt = (wid >> 5) & 7, zg = wid >> 8;
  int z = zbase + zg;
  int s = z >> 2, cls = z & 3, py = cls >> 1, px = cls & 1;
  int l = threadIdx.x, lr = l & 15, lg = l >> 4;
  const u16* Ap = Wt + ((size_t)z * NC + mt * 16 + lr) * LL + lg * 8;
  const u16* B0 = Pb + ((size_t)(zg * LL + ng * 32 + lr)) * LL + lg * 8;
  const u16* B1 = B0 + (size_t)16 * LL;
  f32x4 acc0 = {}, acc1 = {};
#pragma unroll 4
  for (int kc = 0; kc < 32; ++kc) {
    int o = kc * 32;
    s16x8 a  = *(const s16x8*)(Ap + o);
    s16x8 b0 = *(const s16x8*)(B0 + o);
    s16x8 b1 = *(const s16x8*)(B1 + o);
    acc0 = __builtin_amdgcn_mfma_f32_16x16x32_bf16(a, b0, acc0, 0, 0, 0);
    acc1 = __builtin_amdgcn_mfma_f32_16x16x32_bf16(a, b1, acc1, 0, 0, 0);
  }
  int c0 = mt * 16 + lg * 4;
  int nn0 = ng * 32 + lr, nn1 = nn0 + 16;
  size_t ob0 = (size_t)(2 * (nn0 >> 5) + py) * WW + 2 * (nn0 & 31) + px;
  size_t ob1 = (size_t)(2 * (nn1 >> 5) + py) * WW + 2 * (nn1 & 31) + px;
  float* os = out + (size_t)s * NC * HH * WW;
#pragma unroll
  for (int r = 0; r < 4; ++r) {
    os[(size_t)(c0 + r) * (HH * WW) + ob0] = acc0[r] * 0.25f;
    os[(size_t)(c0 + r) * (HH * WW) + ob1] = acc1[r] * 0.25f;
  }
}

extern "C" void kernel_launch(void* const* d_in, const int* in_sizes, int n_in,
                              void* d_out, int out_size, void* d_ws, size_t ws_size,
                              hipStream_t stream) {
  const float* f    = (const float*)d_in[0];
  const float* b    = (const float*)d_in[1];
  const float* mask = (const float*)d_in[2];
  float* out  = (float*)d_out;

  // workspace layout: ~40 MB
  float* buf0 = (float*)d_ws;              // 4,194,304 f (G -> F1 -> yiT)
  float* buf1 = buf0 + 4194304;            // 4,194,304 f (S -> F2 -> Pb alias)
  u16* bsT_hi = (u16*)(buf1 + 4194304);    // 524,288 u16 each
  u16* bsT_lo = bsT_hi + 524288;
  u16* fsT_hi = bsT_lo + 524288;
  u16* fsT_lo = fsT_hi + 524288;
  u16* Wt     = fsT_lo + 524288;           // 2,097,152 u16
  float* nrm  = (float*)(Wt + 2097152);    // 4,096
  float* mmv  = nrm + 4096;                // 4,096
  u16* Pb     = (u16*)buf1;                // alias (F2 dead after softmax_k)

  hipLaunchKernelGGL(prep_T, dim3(256), dim3(256), 0, stream, f, b, bsT_hi, bsT_lo, fsT_hi, fsT_lo);
  hipLaunchKernelGGL(prep_wt, dim3(2048), dim3(256), 0, stream, b, Wt);
  hipLaunchKernelGGL(gram_mfma, dim3(8192), dim3(64), 0, stream, bsT_hi, bsT_lo, fsT_hi, fsT_lo, buf0);
  hipLaunchKernelGGL(norm_mm, dim3(4), dim3(1024), 0, stream, bsT_hi, bsT_lo, mask, nrm, mmv);
  hipLaunchKernelGGL(sbuild, dim3(4, 1024, 4), dim3(256), 0, stream, buf0, nrm, buf1);
  hipLaunchKernelGGL(fuse1, dim3(4, 1024, 4), dim3(256), 0, stream, buf1, buf0);
  hipLaunchKernelGGL(fuse2, dim3(4, 1024, 4), dim3(256), 0, stream, buf0, buf1);
  hipLaunchKernelGGL(softmax_k, dim3(64, 4), dim3(256), 0, stream, buf1, mmv, buf0);
  hipLaunchKernelGGL(build_p, dim3(4096), dim3(256), 0, stream, buf0, Pb, 0);
  hipLaunchKernelGGL(deconv_gemm, dim3(2048), dim3(64), 0, stream, Pb, Wt, out, 0);
  hipLaunchKernelGGL(build_p, dim3(4096), dim3(256), 0, stream, buf0, Pb, 8);
  hipLaunchKernelGGL(deconv_gemm, dim3(2048), dim3(64), 0, stream, Pb, Wt, out, 8);
}

// Round 4
// 211.946 us; speedup vs baseline: 1.4181x; 1.4181x over previous
//
#include <hip/hip_runtime.h>
#include <math.h>

#define NS 4
#define NC 128
#define HH 64
#define WW 64
#define LL 1024   // 32*32

typedef unsigned short u16;
typedef u16 u16x4 __attribute__((ext_vector_type(4)));
typedef short s16x8 __attribute__((ext_vector_type(8)));
typedef float f32x4 __attribute__((ext_vector_type(4)));

__device__ __forceinline__ u16 f2bf(float x) {
  unsigned u = __float_as_uint(x);
  return (u16)((u + 0x7FFFu + ((u >> 16) & 1u)) >> 16);
}
__device__ __forceinline__ float bf2f(u16 h) {
  return __uint_as_float(((unsigned)h) << 16);
}

// ---------------- prep: transposed hi/lo bf16 operands for gram
// bsT/fsT[(s*LL + row)*NC + c] : row-major, c contiguous
__global__ __launch_bounds__(256) void prep_T(const float* __restrict__ f,
                                              const float* __restrict__ b,
                                              u16* __restrict__ bsT_hi, u16* __restrict__ bsT_lo,
                                              u16* __restrict__ fsT_hi, u16* __restrict__ fsT_lo) {
  int idx = blockIdx.x * 256 + threadIdx.x;      // 4*1024*16 = 65536
  int co = (idx & 15) * 8;
  int q  = (idx >> 4) & 1023;
  int s  = idx >> 14;
  int qh = q >> 5, qw = q & 31;
  size_t g0 = ((size_t)(s * NC) * HH + 2 * qh) * WW + 2 * qw;
  u16x4 fh0, fh1, fl0, fl1, bh0, bh1, bl0, bl1;
  u16* fhv[2] = { (u16*)&fh0, (u16*)&fh1 };
  u16* flv[2] = { (u16*)&fl0, (u16*)&fl1 };
  u16* bhv[2] = { (u16*)&bh0, (u16*)&bh1 };
  u16* blv[2] = { (u16*)&bl0, (u16*)&bl1 };
#pragma unroll
  for (int e = 0; e < 8; ++e) {
    size_t off = g0 + (size_t)(co + e) * (HH * WW);
    float xf = f[off], xb = b[off];
    u16 hf = f2bf(xf); u16 lf = f2bf(xf - bf2f(hf));
    u16 hb = f2bf(xb); u16 lb = f2bf(xb - bf2f(hb));
    fhv[e >> 2][e & 3] = hf; flv[e >> 2][e & 3] = lf;
    bhv[e >> 2][e & 3] = hb; blv[e >> 2][e & 3] = lb;
  }
  size_t o = ((size_t)(s * LL) + q) * NC + co;
  *(u16x4*)(fsT_hi + o) = fh0; *(u16x4*)(fsT_hi + o + 4) = fh1;
  *(u16x4*)(fsT_lo + o) = fl0; *(u16x4*)(fsT_lo + o + 4) = fl1;
  *(u16x4*)(bsT_hi + o) = bh0; *(u16x4*)(bsT_hi + o + 4) = bh1;
  *(u16x4*)(bsT_lo + o) = bl0; *(u16x4*)(bsT_lo + o + 4) = bl1;
}

// ---------------- prep: Wt[z][c][k] bf16 = b[s][c][2kh+py][2kw+px], k = kh*32+kw
__global__ __launch_bounds__(256) void prep_wt(const float* __restrict__ b,
                                               u16* __restrict__ Wt) {
  int q = blockIdx.x * 256 + threadIdx.x;        // 524288 quads
  int k4 = (q & 255) * 4;
  int c  = (q >> 8) & 127;
  int z  = q >> 15;
  int s = z >> 2, cls = z & 3, py = cls >> 1, px = cls & 1;
  int kh = k4 >> 5, kw = k4 & 31;
  const float* src = b + ((size_t)(s * NC + c) * HH + 2 * kh + py) * WW + px;
  u16x4 v;
#pragma unroll
  for (int i = 0; i < 4; ++i) v[i] = f2bf(src[2 * (kw + i)]);
  *(u16x4*)(Wt + (size_t)q * 4) = v;
}

// ---------------- gram via split-bf16 MFMA: G[s][p][q] = sum_c bs[c][p]*fs[c][q]
// one wave per block: 1 m-tile (16 p) x 2 n-tiles (32 q), K=128
__global__ __launch_bounds__(64) void gram_mfma(const u16* __restrict__ bsT_hi,
                                                const u16* __restrict__ bsT_lo,
                                                const u16* __restrict__ fsT_hi,
                                                const u16* __restrict__ fsT_lo,
                                                float* __restrict__ G) {
  int wid = blockIdx.x;                 // 8192 = 4s * 64mt * 32ng
  int ng = wid & 31, mt = (wid >> 5) & 63, s = wid >> 11;
  int l = threadIdx.x, lr = l & 15, lg = l >> 4;
  size_t ab  = ((size_t)(s * LL) + mt * 16 + lr) * NC + lg * 8;
  size_t b0b = ((size_t)(s * LL) + ng * 32 + lr) * NC + lg * 8;
  size_t b1b = b0b + (size_t)16 * NC;
  f32x4 acc0 = {}, acc1 = {};
#pragma unroll
  for (int kc = 0; kc < 4; ++kc) {
    int o = kc * 32;
    s16x8 ah  = *(const s16x8*)(bsT_hi + ab + o);
    s16x8 al  = *(const s16x8*)(bsT_lo + ab + o);
    s16x8 bh0 = *(const s16x8*)(fsT_hi + b0b + o);
    s16x8 bl0 = *(const s16x8*)(fsT_lo + b0b + o);
    s16x8 bh1 = *(const s16x8*)(fsT_hi + b1b + o);
    s16x8 bl1 = *(const s16x8*)(fsT_lo + b1b + o);
    acc0 = __builtin_amdgcn_mfma_f32_16x16x32_bf16(ah, bh0, acc0, 0, 0, 0);
    acc0 = __builtin_amdgcn_mfma_f32_16x16x32_bf16(ah, bl0, acc0, 0, 0, 0);
    acc0 = __builtin_amdgcn_mfma_f32_16x16x32_bf16(al, bh0, acc0, 0, 0, 0);
    acc1 = __builtin_amdgcn_mfma_f32_16x16x32_bf16(ah, bh1, acc1, 0, 0, 0);
    acc1 = __builtin_amdgcn_mfma_f32_16x16x32_bf16(ah, bl1, acc1, 0, 0, 0);
    acc1 = __builtin_amdgcn_mfma_f32_16x16x32_bf16(al, bh1, acc1, 0, 0, 0);
  }
  float* Gs = G + ((size_t)s << 20);
  int prow = mt * 16 + lg * 4;
  int q0 = ng * 32 + lr;
#pragma unroll
  for (int r = 0; r < 4; ++r) {
    Gs[(size_t)(prow + r) * LL + q0]      = acc0[r];
    Gs[(size_t)(prow + r) * LL + q0 + 16] = acc1[r];
  }
}

// ---------------- norms (patch L2 incl. +1e-4 per element) and mask means
__global__ __launch_bounds__(1024) void norm_mm(const u16* __restrict__ bsT_hi,
                                                const u16* __restrict__ bsT_lo,
                                                const float* __restrict__ mask,
                                                float* __restrict__ nrm,
                                                float* __restrict__ mmv) {
  int s = blockIdx.x;
  int p = threadIdx.x;             // 1024
  __shared__ float Q[LL];
  __shared__ float M[LL];
  const u16* hb = bsT_hi + ((size_t)(s * LL) + p) * NC;
  const u16* lb = bsT_lo + ((size_t)(s * LL) + p) * NC;
  float q = 0.f;
  for (int co = 0; co < NC; co += 8) {
    s16x8 h = *(const s16x8*)(hb + co);
    s16x8 lo = *(const s16x8*)(lb + co);
#pragma unroll
    for (int e = 0; e < 8; ++e) {
      float v = bf2f((u16)h[e]) + bf2f((u16)lo[e]);
      q += v * v;
    }
  }
  Q[p] = q;
  int ph = p >> 5, pw = p & 31;
  M[p] = mask[s * HH * WW + (2 * ph) * WW + 2 * pw];
  __syncthreads();
  float sum2 = 1152 * 1e-4f;       // sum of the +0.0001 terms (128*3*3)
  float msum = 0.f;
#pragma unroll
  for (int dh = -1; dh <= 1; ++dh)
#pragma unroll
    for (int dw = -1; dw <= 1; ++dw) {
      int h = ph + dh, w = pw + dw;
      if (h >= 0 && h < 32 && w >= 0 && w < 32) {
        sum2 += Q[h * 32 + w];
        msum += M[h * 32 + w];
      }
    }
  nrm[s * LL + p] = sqrtf(sum2);
  mmv[s * LL + p] = msum * (1.f / 9.f);
}

// ---------------- S[p][q] = (sum of 9 diagonal 2D taps of G) / norm[p]
__global__ __launch_bounds__(256) void sbuild(const float* __restrict__ G,
                                              const float* __restrict__ nrm,
                                              float* __restrict__ S) {
  int s = blockIdx.z;
  int p = blockIdx.y;
  int q = blockIdx.x * 256 + threadIdx.x;
  int ph = p >> 5, pw = p & 31, qh = q >> 5, qw = q & 31;
  const float* Gs = G + (size_t)s * LL * LL;
  float acc = 0.f;
#pragma unroll
  for (int dh = -1; dh <= 1; ++dh)
#pragma unroll
    for (int dw = -1; dw <= 1; ++dw) {
      int ph2 = ph + dh, pw2 = pw + dw, qh2 = qh + dh, qw2 = qw + dw;
      if (ph2 >= 0 && ph2 < 32 && pw2 >= 0 && pw2 < 32 &&
          qh2 >= 0 && qh2 < 32 && qw2 >= 0 && qw2 < 32)
        acc += Gs[(size_t)(ph2 * 32 + pw2) * LL + qh2 * 32 + qw2];
    }
  S[(size_t)s * LL * LL + (size_t)p * LL + q] = acc / nrm[s * LL + p];
}

// ---------------- fuse pass 1: flat diagonal 3-tap in (I,J)
__global__ __launch_bounds__(256) void fuse1(const float* __restrict__ S,
                                             float* __restrict__ F1) {
  int s = blockIdx.z;
  int I = blockIdx.y;
  int J = blockIdx.x * 256 + threadIdx.x;
  const float* Ss = S + (size_t)s * LL * LL;
  float v = Ss[(size_t)I * LL + J];
  if (I > 0 && J > 0)           v += Ss[(size_t)(I - 1) * LL + J - 1];
  if (I < LL - 1 && J < LL - 1) v += Ss[(size_t)(I + 1) * LL + J + 1];
  F1[(size_t)s * LL * LL + (size_t)I * LL + J] = v;
}

// ---------------- fuse pass 2: diagonal 3-tap in transposed flattening
__global__ __launch_bounds__(256) void fuse2(const float* __restrict__ F1,
                                             float* __restrict__ F2) {
  int s = blockIdx.z;
  int I = blockIdx.y;                        // ibh*32+ibw
  int J = blockIdx.x * 256 + threadIdx.x;    // fhi*32+fwi
  int ibh = I >> 5, ibw = I & 31, fhi = J >> 5, fwi = J & 31;
  int Ip = ibw * 32 + ibh, Jp = fwi * 32 + fhi;
  const float* F = F1 + (size_t)s * LL * LL;
  float v = 0.f;
#pragma unroll
  for (int d = -1; d <= 1; ++d) {
    int a = Ip + d, bb = Jp + d;
    if (a >= 0 && a < LL && bb >= 0 && bb < LL) {
      int I2 = (a & 31) * 32 + (a >> 5);
      int J2 = (bb & 31) * 32 + (bb >> 5);
      v += F[(size_t)I2 * LL + J2];
    }
  }
  F2[(size_t)s * LL * LL + (size_t)I * LL + J] = v;
}

// ---------------- column softmax over p (with mm applied pre/post), write transposed yiT[q][p]
__global__ __launch_bounds__(256) void softmax_k(const float* __restrict__ F2,
                                                 const float* __restrict__ mmv,
                                                 float* __restrict__ yiT) {
  int s  = blockIdx.y;
  int q0 = blockIdx.x * 16;
  int t  = threadIdx.x;
  int qx = t & 15, pg = t >> 4;
  const float* F  = F2 + (size_t)s * LL * LL;
  const float* mm = mmv + s * LL;
  __shared__ float red[16][17];
  float mx = -1e30f;
  for (int j = 0; j < 64; ++j) {
    int p = pg + 16 * j;
    float v = F[(size_t)p * LL + q0 + qx] * mm[p] * 10.f;
    mx = fmaxf(mx, v);
  }
  red[pg][qx] = mx;
  __syncthreads();
  float m = -1e30f;
  for (int i = 0; i < 16; ++i) m = fmaxf(m, red[i][qx]);
  __syncthreads();
  float sm = 0.f;
  for (int j = 0; j < 64; ++j) {
    int p = pg + 16 * j;
    float v = F[(size_t)p * LL + q0 + qx] * mm[p] * 10.f;
    sm += __expf(v - m);
  }
  red[pg][qx] = sm;
  __syncthreads();
  float tot = 0.f;
  for (int i = 0; i < 16; ++i) tot += red[i][qx];
  float inv = 1.f / tot;
  float* yo = yiT + (size_t)s * LL * LL + (size_t)(q0 + qx) * LL;
  for (int j = 0; j < 64; ++j) {
    int p = pg * 64 + j;
    float v = F[(size_t)p * LL + q0 + qx] * mm[p] * 10.f;
    yo[p] = __expf(v - m) * inv * mm[p];
  }
}

// ---------------- build P matrix (4-tap diagonal sums of yiT) as bf16, k-contiguous
// LDS-staged stencil: one block per (s, n); 9-row neighborhood staged once,
// all 4 parity classes computed from it. Pb[((zg*LL + n)<<10) + k], zg=(s-sbase)*4+cls
__global__ __launch_bounds__(256) void build_p(const float* __restrict__ yiT,
                                               u16* __restrict__ Pb, int sbase) {
  int blk = blockIdx.x;            // 2 sg * 1024 n
  int n   = blk & 1023, sg = blk >> 10;
  int s = sbase + sg;
  int ih = n >> 5, jw = n & 31;
  const float* Y = yiT + ((size_t)s << 20);
  __shared__ float R[9][1024];
  int t = threadIdx.x;
#pragma unroll
  for (int r = 0; r < 9; ++r) {
    int di = r / 3 - 1, dj = r % 3 - 1;
    bool v = ((unsigned)(ih + di) < 32u) && ((unsigned)(jw + dj) < 32u);
    float4 val = v ? *(const float4*)(Y + (size_t)(n + di * 32 + dj) * LL + t * 4)
                   : make_float4(0.f, 0.f, 0.f, 0.f);
    *(float4*)&R[r][t * 4] = val;
  }
  __syncthreads();
  int k0 = t * 4;
  int kh = k0 >> 5;                // constant over the 4 elements
#pragma unroll
  for (int cls = 0; cls < 4; ++cls) {
    int py = cls >> 1, px = cls & 1;
    int sy = py ? 1 : -1, sx = px ? 1 : -1;
    const float* RA = R[4];
    const float* RB = R[(sy + 1) * 3 + 1];
    const float* RC = R[3 + sx + 1];
    const float* RD = R[(sy + 1) * 3 + sx + 1];
    bool mB = (unsigned)(kh + sy) < 32u;
    int ob = 32 * sy;
    u16x4 pk;
#pragma unroll
    for (int e = 0; e < 4; ++e) {
      int k = k0 + e;
      int kw = k & 31;
      bool mC = (unsigned)(kw + sx) < 32u;
      float v = RA[k];
      if (mB) v += RB[k + ob];
      if (mC) v += RC[k + sx];
      if (mB && mC) v += RD[k + ob + sx];
      pk[e] = f2bf(v);
    }
    int zg = sg * 4 + cls;
    *(u16x4*)(Pb + (((size_t)(zg * LL + n)) << 10) + k0) = pk;
  }
}

// ---------------- deconv GEMM, barrier-free, 1 wave/block:
// out[c][n'] = 0.25 * sum_k Wt[z][c][k] * Pb[zg][n][k]
// per wave: 1 m-tile (16 c) x 2 n-tiles (32 n), K=1024
__global__ __launch_bounds__(64) void deconv_gemm(const u16* __restrict__ Pb,
                                                  const u16* __restrict__ Wt,
                                                  float* __restrict__ out, int zbase) {
  int wid = blockIdx.x;                 // 2048 = 8zg * 8mt * 32ng
  int ng = wid & 31, mt = (wid >> 5) & 7, zg = wid >> 8;
  int z = zbase + zg;
  int s = z >> 2, cls = z & 3, py = cls >> 1, px = cls & 1;
  int l = threadIdx.x, lr = l & 15, lg = l >> 4;
  const u16* Ap = Wt + ((size_t)z * NC + mt * 16 + lr) * LL + lg * 8;
  const u16* B0 = Pb + ((size_t)(zg * LL + ng * 32 + lr)) * LL + lg * 8;
  const u16* B1 = B0 + (size_t)16 * LL;
  f32x4 acc0 = {}, acc1 = {};
#pragma unroll 4
  for (int kc = 0; kc < 32; ++kc) {
    int o = kc * 32;
    s16x8 a  = *(const s16x8*)(Ap + o);
    s16x8 b0 = *(const s16x8*)(B0 + o);
    s16x8 b1 = *(const s16x8*)(B1 + o);
    acc0 = __builtin_amdgcn_mfma_f32_16x16x32_bf16(a, b0, acc0, 0, 0, 0);
    acc1 = __builtin_amdgcn_mfma_f32_16x16x32_bf16(a, b1, acc1, 0, 0, 0);
  }
  int c0 = mt * 16 + lg * 4;
  int nn0 = ng * 32 + lr, nn1 = nn0 + 16;
  size_t ob0 = (size_t)(2 * (nn0 >> 5) + py) * WW + 2 * (nn0 & 31) + px;
  size_t ob1 = (size_t)(2 * (nn1 >> 5) + py) * WW + 2 * (nn1 & 31) + px;
  float* os = out + (size_t)s * NC * HH * WW;
#pragma unroll
  for (int r = 0; r < 4; ++r) {
    os[(size_t)(c0 + r) * (HH * WW) + ob0] = acc0[r] * 0.25f;
    os[(size_t)(c0 + r) * (HH * WW) + ob1] = acc1[r] * 0.25f;
  }
}

extern "C" void kernel_launch(void* const* d_in, const int* in_sizes, int n_in,
                              void* d_out, int out_size, void* d_ws, size_t ws_size,
                              hipStream_t stream) {
  const float* f    = (const float*)d_in[0];
  const float* b    = (const float*)d_in[1];
  const float* mask = (const float*)d_in[2];
  float* out  = (float*)d_out;

  // workspace layout: ~40 MB
  float* buf0 = (float*)d_ws;              // 4,194,304 f (G -> F1 -> yiT)
  float* buf1 = buf0 + 4194304;            // 4,194,304 f (S -> F2 -> Pb alias)
  u16* bsT_hi = (u16*)(buf1 + 4194304);    // 524,288 u16 each
  u16* bsT_lo = bsT_hi + 524288;
  u16* fsT_hi = bsT_lo + 524288;
  u16* fsT_lo = fsT_hi + 524288;
  u16* Wt     = fsT_lo + 524288;           // 2,097,152 u16
  float* nrm  = (float*)(Wt + 2097152);    // 4,096
  float* mmv  = nrm + 4096;                // 4,096
  u16* Pb     = (u16*)buf1;                // alias (F2 dead after softmax_k)

  hipLaunchKernelGGL(prep_T, dim3(256), dim3(256), 0, stream, f, b, bsT_hi, bsT_lo, fsT_hi, fsT_lo);
  hipLaunchKernelGGL(prep_wt, dim3(2048), dim3(256), 0, stream, b, Wt);
  hipLaunchKernelGGL(gram_mfma, dim3(8192), dim3(64), 0, stream, bsT_hi, bsT_lo, fsT_hi, fsT_lo, buf0);
  hipLaunchKernelGGL(norm_mm, dim3(4), dim3(1024), 0, stream, bsT_hi, bsT_lo, mask, nrm, mmv);
  hipLaunchKernelGGL(sbuild, dim3(4, 1024, 4), dim3(256), 0, stream, buf0, nrm, buf1);
  hipLaunchKernelGGL(fuse1, dim3(4, 1024, 4), dim3(256), 0, stream, buf1, buf0);
  hipLaunchKernelGGL(fuse2, dim3(4, 1024, 4), dim3(256), 0, stream, buf0, buf1);
  hipLaunchKernelGGL(softmax_k, dim3(64, 4), dim3(256), 0, stream, buf1, mmv, buf0);
  hipLaunchKernelGGL(build_p, dim3(2048), dim3(256), 0, stream, buf0, Pb, 0);
  hipLaunchKernelGGL(deconv_gemm, dim3(2048), dim3(64), 0, stream, Pb, Wt, out, 0);
  hipLaunchKernelGGL(build_p, dim3(2048), dim3(256), 0, stream, buf0, Pb, 2);
  hipLaunchKernelGGL(deconv_gemm, dim3(2048), dim3(64), 0, stream, Pb, Wt, out, 8);
}

// Round 5
// 208.212 us; speedup vs baseline: 1.4435x; 1.0179x over previous
//
#include <hip/hip_runtime.h>
#include <math.h>

#define NS 4
#define NC 128
#define HH 64
#define WW 64
#define LL 1024   // 32*32

typedef unsigned short u16;
typedef u16 u16x4 __attribute__((ext_vector_type(4)));
typedef short s16x8 __attribute__((ext_vector_type(8)));
typedef float f32x4 __attribute__((ext_vector_type(4)));

__device__ __forceinline__ u16 f2bf(float x) {
  unsigned u = __float_as_uint(x);
  return (u16)((u + 0x7FFFu + ((u >> 16) & 1u)) >> 16);
}
__device__ __forceinline__ float bf2f(u16 h) {
  return __uint_as_float(((unsigned)h) << 16);
}

// ---------------- prep: transposed hi/lo bf16 operands for gram
__global__ __launch_bounds__(256) void prep_T(const float* __restrict__ f,
                                              const float* __restrict__ b,
                                              u16* __restrict__ bsT_hi, u16* __restrict__ bsT_lo,
                                              u16* __restrict__ fsT_hi, u16* __restrict__ fsT_lo) {
  int idx = blockIdx.x * 256 + threadIdx.x;      // 4*1024*16 = 65536
  int co = (idx & 15) * 8;
  int q  = (idx >> 4) & 1023;
  int s  = idx >> 14;
  int qh = q >> 5, qw = q & 31;
  size_t g0 = ((size_t)(s * NC) * HH + 2 * qh) * WW + 2 * qw;
  u16x4 fh0, fh1, fl0, fl1, bh0, bh1, bl0, bl1;
  u16* fhv[2] = { (u16*)&fh0, (u16*)&fh1 };
  u16* flv[2] = { (u16*)&fl0, (u16*)&fl1 };
  u16* bhv[2] = { (u16*)&bh0, (u16*)&bh1 };
  u16* blv[2] = { (u16*)&bl0, (u16*)&bl1 };
#pragma unroll
  for (int e = 0; e < 8; ++e) {
    size_t off = g0 + (size_t)(co + e) * (HH * WW);
    float xf = f[off], xb = b[off];
    u16 hf = f2bf(xf); u16 lf = f2bf(xf - bf2f(hf));
    u16 hb = f2bf(xb); u16 lb = f2bf(xb - bf2f(hb));
    fhv[e >> 2][e & 3] = hf; flv[e >> 2][e & 3] = lf;
    bhv[e >> 2][e & 3] = hb; blv[e >> 2][e & 3] = lb;
  }
  size_t o = ((size_t)(s * LL) + q) * NC + co;
  *(u16x4*)(fsT_hi + o) = fh0; *(u16x4*)(fsT_hi + o + 4) = fh1;
  *(u16x4*)(fsT_lo + o) = fl0; *(u16x4*)(fsT_lo + o + 4) = fl1;
  *(u16x4*)(bsT_hi + o) = bh0; *(u16x4*)(bsT_hi + o + 4) = bh1;
  *(u16x4*)(bsT_lo + o) = bl0; *(u16x4*)(bsT_lo + o + 4) = bl1;
}

// ---------------- prep: Wt[z][c][k] bf16
__global__ __launch_bounds__(256) void prep_wt(const float* __restrict__ b,
                                               u16* __restrict__ Wt) {
  int q = blockIdx.x * 256 + threadIdx.x;        // 524288 quads
  int k4 = (q & 255) * 4;
  int c  = (q >> 8) & 127;
  int z  = q >> 15;
  int s = z >> 2, cls = z & 3, py = cls >> 1, px = cls & 1;
  int kh = k4 >> 5, kw = k4 & 31;
  const float* src = b + ((size_t)(s * NC + c) * HH + 2 * kh + py) * WW + px;
  u16x4 v;
#pragma unroll
  for (int i = 0; i < 4; ++i) v[i] = f2bf(src[2 * (kw + i)]);
  *(u16x4*)(Wt + (size_t)q * 4) = v;
}

// ---------------- gram via split-bf16 MFMA, 4 waves/block, 4 n-tiles/wave,
// 2-deep register prefetch over K=128
__global__ __launch_bounds__(256) void gram_mfma(const u16* __restrict__ bsT_hi,
                                                 const u16* __restrict__ bsT_lo,
                                                 const u16* __restrict__ fsT_hi,
                                                 const u16* __restrict__ fsT_lo,
                                                 float* __restrict__ G) {
  int wid = blockIdx.x * 4 + (threadIdx.x >> 6);  // 4096 = 4s * 64mt * 16ngg
  int ngg = wid & 15, mt = (wid >> 4) & 63, s = wid >> 10;
  int l = threadIdx.x & 63, lr = l & 15, lg = l >> 4;
  const u16* Ah = bsT_hi + ((size_t)(s * LL) + mt * 16 + lr) * NC + lg * 8;
  const u16* Al = bsT_lo + ((size_t)(s * LL) + mt * 16 + lr) * NC + lg * 8;
  size_t bbase = ((size_t)(s * LL) + ngg * 64 + lr) * NC + lg * 8;
  f32x4 acc[4] = {};
  s16x8 ah0, al0, bh0[4], bl0[4];
  s16x8 ah1, al1, bh1[4], bl1[4];
  auto LD = [&](int kc, s16x8& ah, s16x8& al, s16x8* bh, s16x8* bl) {
    int o = kc * 32;
    ah = *(const s16x8*)(Ah + o);
    al = *(const s16x8*)(Al + o);
#pragma unroll
    for (int nt = 0; nt < 4; ++nt) {
      bh[nt] = *(const s16x8*)(fsT_hi + bbase + nt * 16 * NC + o);
      bl[nt] = *(const s16x8*)(fsT_lo + bbase + nt * 16 * NC + o);
    }
  };
  auto ST = [&](s16x8& ah, s16x8& al, s16x8* bh, s16x8* bl) {
#pragma unroll
    for (int nt = 0; nt < 4; ++nt) {
      acc[nt] = __builtin_amdgcn_mfma_f32_16x16x32_bf16(ah, bh[nt], acc[nt], 0, 0, 0);
      acc[nt] = __builtin_amdgcn_mfma_f32_16x16x32_bf16(ah, bl[nt], acc[nt], 0, 0, 0);
      acc[nt] = __builtin_amdgcn_mfma_f32_16x16x32_bf16(al, bh[nt], acc[nt], 0, 0, 0);
    }
  };
  LD(0, ah0, al0, bh0, bl0);
  LD(1, ah1, al1, bh1, bl1);
  ST(ah0, al0, bh0, bl0);
  LD(2, ah0, al0, bh0, bl0);
  ST(ah1, al1, bh1, bl1);
  LD(3, ah1, al1, bh1, bl1);
  ST(ah0, al0, bh0, bl0);
  ST(ah1, al1, bh1, bl1);
  float* Gs = G + ((size_t)s << 20);
  int prow = mt * 16 + lg * 4;
#pragma unroll
  for (int nt = 0; nt < 4; ++nt) {
    int q0 = ngg * 64 + nt * 16 + lr;
#pragma unroll
    for (int r = 0; r < 4; ++r)
      Gs[(size_t)(prow + r) * LL + q0] = acc[nt][r];
  }
}

// ---------------- norms and mask means
__global__ __launch_bounds__(1024) void norm_mm(const u16* __restrict__ bsT_hi,
                                                const u16* __restrict__ bsT_lo,
                                                const float* __restrict__ mask,
                                                float* __restrict__ nrm,
                                                float* __restrict__ mmv) {
  int s = blockIdx.x;
  int p = threadIdx.x;             // 1024
  __shared__ float Q[LL];
  __shared__ float M[LL];
  const u16* hb = bsT_hi + ((size_t)(s * LL) + p) * NC;
  const u16* lb = bsT_lo + ((size_t)(s * LL) + p) * NC;
  float q = 0.f;
  for (int co = 0; co < NC; co += 8) {
    s16x8 h = *(const s16x8*)(hb + co);
    s16x8 lo = *(const s16x8*)(lb + co);
#pragma unroll
    for (int e = 0; e < 8; ++e) {
      float v = bf2f((u16)h[e]) + bf2f((u16)lo[e]);
      q += v * v;
    }
  }
  Q[p] = q;
  int ph = p >> 5, pw = p & 31;
  M[p] = mask[s * HH * WW + (2 * ph) * WW + 2 * pw];
  __syncthreads();
  float sum2 = 1152 * 1e-4f;
  float msum = 0.f;
#pragma unroll
  for (int dh = -1; dh <= 1; ++dh)
#pragma unroll
    for (int dw = -1; dw <= 1; ++dw) {
      int h = ph + dh, w = pw + dw;
      if (h >= 0 && h < 32 && w >= 0 && w < 32) {
        sum2 += Q[h * 32 + w];
        msum += M[h * 32 + w];
      }
    }
  nrm[s * LL + p] = sqrtf(sum2);
  mmv[s * LL + p] = msum * (1.f / 9.f);
}

// ---------------- S[p][q] = (sum of 9 diagonal 2D taps of G) / norm[p]
__global__ __launch_bounds__(256) void sbuild(const float* __restrict__ G,
                                              const float* __restrict__ nrm,
                                              float* __restrict__ S) {
  int s = blockIdx.z;
  int p = blockIdx.y;
  int q = blockIdx.x * 256 + threadIdx.x;
  int ph = p >> 5, pw = p & 31, qh = q >> 5, qw = q & 31;
  const float* Gs = G + (size_t)s * LL * LL;
  float acc = 0.f;
#pragma unroll
  for (int dh = -1; dh <= 1; ++dh)
#pragma unroll
    for (int dw = -1; dw <= 1; ++dw) {
      int ph2 = ph + dh, pw2 = pw + dw, qh2 = qh + dh, qw2 = qw + dw;
      if (ph2 >= 0 && ph2 < 32 && pw2 >= 0 && pw2 < 32 &&
          qh2 >= 0 && qh2 < 32 && qw2 >= 0 && qw2 < 32)
        acc += Gs[(size_t)(ph2 * 32 + pw2) * LL + qh2 * 32 + qw2];
    }
  S[(size_t)s * LL * LL + (size_t)p * LL + q] = acc / nrm[s * LL + p];
}

// ---------------- fuse pass 1: flat diagonal 3-tap in (I,J)
__global__ __launch_bounds__(256) void fuse1(const float* __restrict__ S,
                                             float* __restrict__ F1) {
  int s = blockIdx.z;
  int I = blockIdx.y;
  int J = blockIdx.x * 256 + threadIdx.x;
  const float* Ss = S + (size_t)s * LL * LL;
  float v = Ss[(size_t)I * LL + J];
  if (I > 0 && J > 0)           v += Ss[(size_t)(I - 1) * LL + J - 1];
  if (I < LL - 1 && J < LL - 1) v += Ss[(size_t)(I + 1) * LL + J + 1];
  F1[(size_t)s * LL * LL + (size_t)I * LL + J] = v;
}

// ---------------- fused fuse2 + column softmax: F2 computed into LDS, softmax
// over p from LDS, write transposed yiT[q][p]
__global__ __launch_bounds__(256) void fuse2_softmax(const float* __restrict__ F1,
                                                     const float* __restrict__ mmv,
                                                     float* __restrict__ yiT) {
  int s  = blockIdx.y;
  int q0 = blockIdx.x * 8;
  __shared__ float V[1024][9];     // padded stride-9: conflict-free both phases
  __shared__ float mmL[1024];
  __shared__ float red[32][8];
  __shared__ float colS[8];
  int t = threadIdx.x;
  const float* F  = F1 + ((size_t)s << 20);
  const float* mm = mmv + s * LL;
  for (int i = t; i < 1024; i += 256) mmL[i] = mm[i];
  __syncthreads();
  int qx = t & 7, pg = t >> 3;     // pg 0..31
  int q = q0 + qx;
  int Jp = (q & 31) * 32 + (q >> 5);
  float lmax = -1e30f;
  for (int j = 0; j < 32; ++j) {
    int p = pg * 32 + j;
    int Ip = (p & 31) * 32 + (p >> 5);
    float v = 0.f;
#pragma unroll
    for (int d = -1; d <= 1; ++d) {
      int a = Ip + d, bb = Jp + d;
      if ((unsigned)a < 1024u && (unsigned)bb < 1024u) {
        int I2 = (a & 31) * 32 + (a >> 5);
        int J2 = (bb & 31) * 32 + (bb >> 5);
        v += F[(size_t)I2 * LL + J2];
      }
    }
    v *= mmL[p] * 10.f;
    V[p][qx] = v;
    lmax = fmaxf(lmax, v);
  }
  red[pg][qx] = lmax;
  __syncthreads();
  float m = -1e30f;
#pragma unroll
  for (int i = 0; i < 32; ++i) m = fmaxf(m, red[i][qx]);
  __syncthreads();                 // all reads of red done before reuse
  float lsum = 0.f;
  for (int j = 0; j < 32; ++j) {
    int p = pg * 32 + j;
    float e = __expf(V[p][qx] - m);
    V[p][qx] = e;
    lsum += e;
  }
  red[pg][qx] = lsum;
  __syncthreads();
  float tot = 0.f;
#pragma unroll
  for (int i = 0; i < 32; ++i) tot += red[i][qx];
  if (pg == 0) colS[qx] = 1.f / tot;
  __syncthreads();
  // coalesced write phase: remap lanes so p is contiguous across a half-wave
  int qx2 = t >> 5, pl = t & 31;
  float inv2 = colS[qx2];
  float* yo = yiT + ((size_t)s << 20) + (size_t)(q0 + qx2) * LL;
  for (int j = 0; j < 32; ++j) {
    int p = j * 32 + pl;
    yo[p] = V[p][qx2] * inv2 * mmL[p];
  }
}

// ---------------- build P matrix (4-tap diagonal sums of yiT) as bf16
__global__ __launch_bounds__(256) void build_p(const float* __restrict__ yiT,
                                               u16* __restrict__ Pb, int sbase) {
  int blk = blockIdx.x;            // 2 sg * 1024 n
  int n   = blk & 1023, sg = blk >> 10;
  int s = sbase + sg;
  int ih = n >> 5, jw = n & 31;
  const float* Y = yiT + ((size_t)s << 20);
  __shared__ float R[9][1024];
  int t = threadIdx.x;
#pragma unroll
  for (int r = 0; r < 9; ++r) {
    int di = r / 3 - 1, dj = r % 3 - 1;
    bool v = ((unsigned)(ih + di) < 32u) && ((unsigned)(jw + dj) < 32u);
    float4 val = v ? *(const float4*)(Y + (size_t)(n + di * 32 + dj) * LL + t * 4)
                   : make_float4(0.f, 0.f, 0.f, 0.f);
    *(float4*)&R[r][t * 4] = val;
  }
  __syncthreads();
  int k0 = t * 4;
  int kh = k0 >> 5;
#pragma unroll
  for (int cls = 0; cls < 4; ++cls) {
    int py = cls >> 1, px = cls & 1;
    int sy = py ? 1 : -1, sx = px ? 1 : -1;
    const float* RA = R[4];
    const float* RB = R[(sy + 1) * 3 + 1];
    const float* RC = R[3 + sx + 1];
    const float* RD = R[(sy + 1) * 3 + sx + 1];
    bool mB = (unsigned)(kh + sy) < 32u;
    int ob = 32 * sy;
    u16x4 pk;
#pragma unroll
    for (int e = 0; e < 4; ++e) {
      int k = k0 + e;
      int kw = k & 31;
      bool mC = (unsigned)(kw + sx) < 32u;
      float v = RA[k];
      if (mB) v += RB[k + ob];
      if (mC) v += RC[k + sx];
      if (mB && mC) v += RD[k + ob + sx];
      pk[e] = f2bf(v);
    }
    int zg = sg * 4 + cls;
    *(u16x4*)(Pb + (((size_t)(zg * LL + n)) << 10) + k0) = pk;
  }
}

// ---------------- deconv GEMM, 4 waves/block, 4-deep register prefetch, K=1024
__global__ __launch_bounds__(256) void deconv_gemm(const u16* __restrict__ Pb,
                                                   const u16* __restrict__ Wt,
                                                   float* __restrict__ out, int zbase) {
  int wid = blockIdx.x * 4 + (threadIdx.x >> 6);  // 2048 = 8zg * 8mt * 32ng
  int ng = wid & 31, mt = (wid >> 5) & 7, zg = wid >> 8;
  int z = zbase + zg;
  int s = z >> 2, cls = z & 3, py = cls >> 1, px = cls & 1;
  int l = threadIdx.x & 63, lr = l & 15, lg = l >> 4;
  const u16* Ap = Wt + ((size_t)z * NC + mt * 16 + lr) * LL + lg * 8;
  const u16* B0 = Pb + ((size_t)(zg * LL + ng * 32 + lr)) * LL + lg * 8;
  const u16* B1 = B0 + (size_t)16 * LL;
  f32x4 acc0 = {}, acc1 = {};
  s16x8 A0, A1, A2, A3, P0, P1, P2, P3, Q0, Q1, Q2, Q3;
  auto LD = [&](int kc, s16x8& a, s16x8& p, s16x8& qq) {
    int o = kc * 32;
    a  = *(const s16x8*)(Ap + o);
    p  = *(const s16x8*)(B0 + o);
    qq = *(const s16x8*)(B1 + o);
  };
  auto ST = [&](s16x8& a, s16x8& p, s16x8& qq) {
    acc0 = __builtin_amdgcn_mfma_f32_16x16x32_bf16(a, p,  acc0, 0, 0, 0);
    acc1 = __builtin_amdgcn_mfma_f32_16x16x32_bf16(a, qq, acc1, 0, 0, 0);
  };
  LD(0, A0, P0, Q0); LD(1, A1, P1, Q1); LD(2, A2, P2, Q2); LD(3, A3, P3, Q3);
#pragma unroll
  for (int kc = 0; kc < 32; kc += 4) {
    ST(A0, P0, Q0); if (kc + 4 < 32) LD(kc + 4, A0, P0, Q0);
    ST(A1, P1, Q1); if (kc + 5 < 32) LD(kc + 5, A1, P1, Q1);
    ST(A2, P2, Q2); if (kc + 6 < 32) LD(kc + 6, A2, P2, Q2);
    ST(A3, P3, Q3); if (kc + 7 < 32) LD(kc + 7, A3, P3, Q3);
  }
  int c0 = mt * 16 + lg * 4;
  int nn0 = ng * 32 + lr, nn1 = nn0 + 16;
  size_t ob0 = (size_t)(2 * (nn0 >> 5) + py) * WW + 2 * (nn0 & 31) + px;
  size_t ob1 = (size_t)(2 * (nn1 >> 5) + py) * WW + 2 * (nn1 & 31) + px;
  float* os = out + (size_t)s * NC * HH * WW;
#pragma unroll
  for (int r = 0; r < 4; ++r) {
    os[(size_t)(c0 + r) * (HH * WW) + ob0] = acc0[r] * 0.25f;
    os[(size_t)(c0 + r) * (HH * WW) + ob1] = acc1[r] * 0.25f;
  }
}

extern "C" void kernel_launch(void* const* d_in, const int* in_sizes, int n_in,
                              void* d_out, int out_size, void* d_ws, size_t ws_size,
                              hipStream_t stream) {
  const float* f    = (const float*)d_in[0];
  const float* b    = (const float*)d_in[1];
  const float* mask = (const float*)d_in[2];
  float* out  = (float*)d_out;

  // workspace layout: ~40 MB
  float* buf0 = (float*)d_ws;              // 4,194,304 f (G -> F1 -> Pb alias)
  float* buf1 = buf0 + 4194304;            // 4,194,304 f (S -> yiT)
  u16* bsT_hi = (u16*)(buf1 + 4194304);    // 524,288 u16 each
  u16* bsT_lo = bsT_hi + 524288;
  u16* fsT_hi = bsT_lo + 524288;
  u16* fsT_lo = fsT_hi + 524288;
  u16* Wt     = fsT_lo + 524288;           // 2,097,152 u16
  float* nrm  = (float*)(Wt + 2097152);    // 4,096
  float* mmv  = nrm + 4096;                // 4,096
  u16* Pb     = (u16*)buf0;                // alias (F1 dead after fuse2_softmax)

  hipLaunchKernelGGL(prep_T, dim3(256), dim3(256), 0, stream, f, b, bsT_hi, bsT_lo, fsT_hi, fsT_lo);
  hipLaunchKernelGGL(prep_wt, dim3(2048), dim3(256), 0, stream, b, Wt);
  hipLaunchKernelGGL(gram_mfma, dim3(1024), dim3(256), 0, stream, bsT_hi, bsT_lo, fsT_hi, fsT_lo, buf0);
  hipLaunchKernelGGL(norm_mm, dim3(4), dim3(1024), 0, stream, bsT_hi, bsT_lo, mask, nrm, mmv);
  hipLaunchKernelGGL(sbuild, dim3(4, 1024, 4), dim3(256), 0, stream, buf0, nrm, buf1);
  hipLaunchKernelGGL(fuse1, dim3(4, 1024, 4), dim3(256), 0, stream, buf1, buf0);
  hipLaunchKernelGGL(fuse2_softmax, dim3(128, 4), dim3(256), 0, stream, buf0, mmv, buf1);
  hipLaunchKernelGGL(build_p, dim3(2048), dim3(256), 0, stream, buf1, Pb, 0);
  hipLaunchKernelGGL(deconv_gemm, dim3(512), dim3(256), 0, stream, Pb, Wt, out, 0);
  hipLaunchKernelGGL(build_p, dim3(2048), dim3(256), 0, stream, buf1, Pb, 2);
  hipLaunchKernelGGL(deconv_gemm, dim3(512), dim3(256), 0, stream, Pb, Wt, out, 8);
}

// Round 6
// 178.269 us; speedup vs baseline: 1.6860x; 1.1680x over previous
//
#include <hip/hip_runtime.h>
#include <math.h>

#define NS 4
#define NC 128
#define HH 64
#define WW 64
#define LL 1024   // 32*32

typedef unsigned short u16;
typedef u16 u16x4 __attribute__((ext_vector_type(4)));
typedef short s16x8 __attribute__((ext_vector_type(8)));
typedef float f32x4 __attribute__((ext_vector_type(4)));

__device__ __forceinline__ u16 f2bf(float x) {
  unsigned u = __float_as_uint(x);
  return (u16)((u + 0x7FFFu + ((u >> 16) & 1u)) >> 16);
}
__device__ __forceinline__ float bf2f(u16 h) {
  return __uint_as_float(((unsigned)h) << 16);
}

// ---------------- prep: hi/lo bf16 operands (rows contiguous in c) + Q[s][p]=patch ssq
__global__ __launch_bounds__(256) void prep(const float* __restrict__ f,
                                            const float* __restrict__ b,
                                            u16* __restrict__ bsT_hi, u16* __restrict__ bsT_lo,
                                            u16* __restrict__ fsT_hi, u16* __restrict__ fsT_lo,
                                            float* __restrict__ Q) {
  int t = threadIdx.x;
  int idx = blockIdx.x * 256 + t;                // 65536 = 4s*1024q*16cog
  int co = (idx & 15) * 8;
  int q  = (idx >> 4) & 1023;
  int s  = idx >> 14;
  int qh = q >> 5, qw = q & 31;
  size_t g0 = ((size_t)(s * NC) * HH + 2 * qh) * WW + 2 * qw;
  u16x4 fh0, fh1, fl0, fl1, bh0, bh1, bl0, bl1;
  u16* fhv[2] = { (u16*)&fh0, (u16*)&fh1 };
  u16* flv[2] = { (u16*)&fl0, (u16*)&fl1 };
  u16* bhv[2] = { (u16*)&bh0, (u16*)&bh1 };
  u16* blv[2] = { (u16*)&bl0, (u16*)&bl1 };
  float ssq = 0.f;
#pragma unroll
  for (int e = 0; e < 8; ++e) {
    size_t off = g0 + (size_t)(co + e) * (HH * WW);
    float xf = f[off], xb = b[off];
    ssq += xb * xb;
    u16 hf = f2bf(xf); u16 lf = f2bf(xf - bf2f(hf));
    u16 hb = f2bf(xb); u16 lb = f2bf(xb - bf2f(hb));
    fhv[e >> 2][e & 3] = hf; flv[e >> 2][e & 3] = lf;
    bhv[e >> 2][e & 3] = hb; blv[e >> 2][e & 3] = lb;
  }
  size_t o = ((size_t)(s * LL) + q) * NC + co;
  *(u16x4*)(fsT_hi + o) = fh0; *(u16x4*)(fsT_hi + o + 4) = fh1;
  *(u16x4*)(fsT_lo + o) = fl0; *(u16x4*)(fsT_lo + o + 4) = fl1;
  *(u16x4*)(bsT_hi + o) = bh0; *(u16x4*)(bsT_hi + o + 4) = bh1;
  *(u16x4*)(bsT_lo + o) = bl0; *(u16x4*)(bsT_lo + o + 4) = bl1;
  __shared__ float SS[256];
  SS[t] = ssq;
  __syncthreads();
  if (t < 16) {
    float sum = 0.f;
#pragma unroll
    for (int j = 0; j < 16; ++j) sum += SS[t * 16 + j];
    Q[s * LL + ((blockIdx.x * 16 + t) & 1023)] = sum;
  }
}

// ---------------- prep: Wt[z][c][k] bf16
__global__ __launch_bounds__(256) void prep_wt(const float* __restrict__ b,
                                               u16* __restrict__ Wt) {
  int q = blockIdx.x * 256 + threadIdx.x;        // 524288 quads
  int k4 = (q & 255) * 4;
  int c  = (q >> 8) & 127;
  int z  = q >> 15;
  int s = z >> 2, cls = z & 3, py = cls >> 1, px = cls & 1;
  int kh = k4 >> 5, kw = k4 & 31;
  const float* src = b + ((size_t)(s * NC + c) * HH + 2 * kh + py) * WW + px;
  u16x4 v;
#pragma unroll
  for (int i = 0; i < 4; ++i) v[i] = f2bf(src[2 * (kw + i)]);
  *(u16x4*)(Wt + (size_t)q * 4) = v;
}

// ---------------- aux: nrm[p] (9-tap of Q + eps) and mmv[p]
__global__ __launch_bounds__(1024) void aux_nrm(const float* __restrict__ Q,
                                                const float* __restrict__ mask,
                                                float* __restrict__ nrm,
                                                float* __restrict__ mmv) {
  int s = blockIdx.x;
  int p = threadIdx.x;
  __shared__ float Ql[LL];
  __shared__ float M[LL];
  Ql[p] = Q[s * LL + p];
  int ph = p >> 5, pw = p & 31;
  M[p] = mask[s * HH * WW + (2 * ph) * WW + 2 * pw];
  __syncthreads();
  float sum2 = 1152 * 1e-4f;
  float msum = 0.f;
#pragma unroll
  for (int dh = -1; dh <= 1; ++dh)
#pragma unroll
    for (int dw = -1; dw <= 1; ++dw) {
      int h = ph + dh, w = pw + dw;
      if (h >= 0 && h < 32 && w >= 0 && w < 32) {
        sum2 += Ql[h * 32 + w];
        msum += M[h * 32 + w];
      }
    }
  nrm[s * LL + p] = sqrtf(sum2);
  mmv[s * LL + p] = msum * (1.f / 9.f);
}

// ---------------- Gt[q][p] = sum_c fs[c][q]*bs[c][p], split-bf16 MFMA,
// 4 waves/block, 4 n-tiles/wave, 2-deep prefetch over K=128
__global__ __launch_bounds__(256) void gram_mfma(const u16* __restrict__ aT_hi,
                                                 const u16* __restrict__ aT_lo,
                                                 const u16* __restrict__ bT_hi,
                                                 const u16* __restrict__ bT_lo,
                                                 float* __restrict__ G) {
  int wid = blockIdx.x * 4 + (threadIdx.x >> 6);  // 4096 = 4s * 64mt * 16ngg
  int ngg = wid & 15, mt = (wid >> 4) & 63, s = wid >> 10;
  int l = threadIdx.x & 63, lr = l & 15, lg = l >> 4;
  const u16* Ah = aT_hi + ((size_t)(s * LL) + mt * 16 + lr) * NC + lg * 8;
  const u16* Al = aT_lo + ((size_t)(s * LL) + mt * 16 + lr) * NC + lg * 8;
  size_t bbase = ((size_t)(s * LL) + ngg * 64 + lr) * NC + lg * 8;
  f32x4 acc[4] = {};
  s16x8 ah0, al0, bh0[4], bl0[4];
  s16x8 ah1, al1, bh1[4], bl1[4];
  auto LD = [&](int kc, s16x8& ah, s16x8& al, s16x8* bh, s16x8* bl) {
    int o = kc * 32;
    ah = *(const s16x8*)(Ah + o);
    al = *(const s16x8*)(Al + o);
#pragma unroll
    for (int nt = 0; nt < 4; ++nt) {
      bh[nt] = *(const s16x8*)(bT_hi + bbase + nt * 16 * NC + o);
      bl[nt] = *(const s16x8*)(bT_lo + bbase + nt * 16 * NC + o);
    }
  };
  auto ST = [&](s16x8& ah, s16x8& al, s16x8* bh, s16x8* bl) {
#pragma unroll
    for (int nt = 0; nt < 4; ++nt) {
      acc[nt] = __builtin_amdgcn_mfma_f32_16x16x32_bf16(ah, bh[nt], acc[nt], 0, 0, 0);
      acc[nt] = __builtin_amdgcn_mfma_f32_16x16x32_bf16(ah, bl[nt], acc[nt], 0, 0, 0);
      acc[nt] = __builtin_amdgcn_mfma_f32_16x16x32_bf16(al, bh[nt], acc[nt], 0, 0, 0);
    }
  };
  LD(0, ah0, al0, bh0, bl0);
  LD(1, ah1, al1, bh1, bl1);
  ST(ah0, al0, bh0, bl0);
  LD(2, ah0, al0, bh0, bl0);
  ST(ah1, al1, bh1, bl1);
  LD(3, ah1, al1, bh1, bl1);
  ST(ah0, al0, bh0, bl0);
  ST(ah1, al1, bh1, bl1);
  float* Gs = G + ((size_t)s << 20);
  int qrow = mt * 16 + lg * 4;
#pragma unroll
  for (int nt = 0; nt < 4; ++nt) {
    int p0 = ngg * 64 + nt * 16 + lr;
#pragma unroll
    for (int r = 0; r < 4; ++r)
      Gs[(size_t)(qrow + r) * LL + p0] = acc[nt][r];
  }
}

// ---------------- St[q][p] = (9-tap 2D-clipped diagonal of Gt) / nrm[p]
__global__ __launch_bounds__(256) void sbuildT(const float* __restrict__ Gt,
                                               const float* __restrict__ nrm,
                                               float* __restrict__ St) {
  int s = blockIdx.z;
  int q = blockIdx.y;
  int p = blockIdx.x * 256 + threadIdx.x;
  int qh = q >> 5, qw = q & 31, ph = p >> 5, pw = p & 31;
  const float* Gs = Gt + ((size_t)s << 20);
  float acc = 0.f;
#pragma unroll
  for (int dh = -1; dh <= 1; ++dh)
#pragma unroll
    for (int dw = -1; dw <= 1; ++dw) {
      int ph2 = ph + dh, pw2 = pw + dw, qh2 = qh + dh, qw2 = qw + dw;
      if (ph2 >= 0 && ph2 < 32 && pw2 >= 0 && pw2 < 32 &&
          qh2 >= 0 && qh2 < 32 && qw2 >= 0 && qw2 < 32)
        acc += Gs[(size_t)(qh2 * 32 + qw2) * LL + ph2 * 32 + pw2];
    }
  St[((size_t)s << 20) + (size_t)q * LL + p] = acc / nrm[s * LL + p];
}

// ---------------- fused fuse1 + fuse2 + row-softmax (one wave per output row q)
// F2t[q][p] = sum_{d2,d1} St[Rq(d2)+d1][Rp(d2)+d1]  (flat bounds + T-edge remaps)
// then softmax over p with mm pre/post scaling; writes yiT[q][p]
__global__ __launch_bounds__(256) void fuse12_softmax(const float* __restrict__ St,
                                                      const float* __restrict__ mmv,
                                                      float* __restrict__ yiT) {
  int g = blockIdx.x * 4 + (threadIdx.x >> 6);   // 4096 rows
  int s = g >> 10, q = g & 1023;
  int lane = threadIdx.x & 63;
  const float* Ss = St + ((size_t)s << 20);
  const float* mm = mmv + s * LL;
  int qh = q >> 5, qw = q & 31;
  int rq[3]; bool vq[3];
  if (qh > 0)      { rq[0] = q - 32;        vq[0] = true; }
  else if (qw > 0) { rq[0] = 992 + qw - 1;  vq[0] = true; }
  else             { rq[0] = 0;             vq[0] = false; }
  rq[1] = q; vq[1] = true;
  if (qh < 31)      { rq[2] = q + 32;   vq[2] = true; }
  else if (qw < 31) { rq[2] = qw + 1;   vq[2] = true; }
  else              { rq[2] = 0;        vq[2] = false; }
  float v[16];
  float mx = -1e30f;
#pragma unroll
  for (int i = 0; i < 16; ++i) {
    int p = i * 64 + lane;
    int ph = p >> 5, pw = p & 31;
    int rp[3]; bool vp[3];
    if (ph > 0)      { rp[0] = p - 32;        vp[0] = true; }
    else if (pw > 0) { rp[0] = 992 + pw - 1;  vp[0] = true; }
    else             { rp[0] = 0;             vp[0] = false; }
    rp[1] = p; vp[1] = true;
    if (ph < 31)      { rp[2] = p + 32;   vp[2] = true; }
    else if (pw < 31) { rp[2] = pw + 1;   vp[2] = true; }
    else              { rp[2] = 0;        vp[2] = false; }
    float acc = 0.f;
#pragma unroll
    for (int d2 = 0; d2 < 3; ++d2) {
      if (vq[d2] && vp[d2]) {
#pragma unroll
        for (int d1 = -1; d1 <= 1; ++d1) {
          int rr = rq[d2] + d1, cc = rp[d2] + d1;
          if ((unsigned)rr < 1024u && (unsigned)cc < 1024u)
            acc += Ss[(size_t)rr * LL + cc];
        }
      }
    }
    float val = acc * mm[p] * 10.f;
    v[i] = val;
    mx = fmaxf(mx, val);
  }
#pragma unroll
  for (int o = 32; o; o >>= 1) mx = fmaxf(mx, __shfl_xor(mx, o));
  float sum = 0.f;
#pragma unroll
  for (int i = 0; i < 16; ++i) { v[i] = __expf(v[i] - mx); sum += v[i]; }
#pragma unroll
  for (int o = 32; o; o >>= 1) sum += __shfl_xor(sum, o);
  float inv = 1.f / sum;
  float* yo = yiT + ((size_t)s << 20) + (size_t)q * LL;
#pragma unroll
  for (int i = 0; i < 16; ++i) {
    int p = i * 64 + lane;
    yo[p] = v[i] * inv * mm[p];
  }
}

// ---------------- build P (4-tap diagonal sums of yiT) as bf16, all 16 z
__global__ __launch_bounds__(256) void build_p(const float* __restrict__ yiT,
                                               u16* __restrict__ Pb) {
  int blk = blockIdx.x;            // 4096 = 4 s * 1024 n
  int n   = blk & 1023, s = blk >> 10;
  int ih = n >> 5, jw = n & 31;
  const float* Y = yiT + ((size_t)s << 20);
  __shared__ float R[9][1024];
  int t = threadIdx.x;
#pragma unroll
  for (int r = 0; r < 9; ++r) {
    int di = r / 3 - 1, dj = r % 3 - 1;
    bool v = ((unsigned)(ih + di) < 32u) && ((unsigned)(jw + dj) < 32u);
    float4 val = v ? *(const float4*)(Y + (size_t)(n + di * 32 + dj) * LL + t * 4)
                   : make_float4(0.f, 0.f, 0.f, 0.f);
    *(float4*)&R[r][t * 4] = val;
  }
  __syncthreads();
  int k0 = t * 4;
  int kh = k0 >> 5;
#pragma unroll
  for (int cls = 0; cls < 4; ++cls) {
    int py = cls >> 1, px = cls & 1;
    int sy = py ? 1 : -1, sx = px ? 1 : -1;
    const float* RA = R[4];
    const float* RB = R[(sy + 1) * 3 + 1];
    const float* RC = R[3 + sx + 1];
    const float* RD = R[(sy + 1) * 3 + sx + 1];
    bool mB = (unsigned)(kh + sy) < 32u;
    int ob = 32 * sy;
    u16x4 pk;
#pragma unroll
    for (int e = 0; e < 4; ++e) {
      int k = k0 + e;
      int kw = k & 31;
      bool mC = (unsigned)(kw + sx) < 32u;
      float v = RA[k];
      if (mB) v += RB[k + ob];
      if (mC) v += RC[k + sx];
      if (mB && mC) v += RD[k + ob + sx];
      pk[e] = f2bf(v);
    }
    int zg = s * 4 + cls;
    *(u16x4*)(Pb + (((size_t)(zg * LL + n)) << 10) + k0) = pk;
  }
}

// ---------------- deconv GEMM, all 16 z, 4 waves/block, 4-deep prefetch, K=1024
__global__ __launch_bounds__(256) void deconv_gemm(const u16* __restrict__ Pb,
                                                   const u16* __restrict__ Wt,
                                                   float* __restrict__ out) {
  int wid = blockIdx.x * 4 + (threadIdx.x >> 6);  // 4096 = 16z * 8mt * 32ng
  int ng = wid & 31, mt = (wid >> 5) & 7, z = wid >> 8;
  int s = z >> 2, cls = z & 3, py = cls >> 1, px = cls & 1;
  int l = threadIdx.x & 63, lr = l & 15, lg = l >> 4;
  const u16* Ap = Wt + ((size_t)z * NC + mt * 16 + lr) * LL + lg * 8;
  const u16* B0 = Pb + ((size_t)(z * LL + ng * 32 + lr)) * LL + lg * 8;
  const u16* B1 = B0 + (size_t)16 * LL;
  f32x4 acc0 = {}, acc1 = {};
  s16x8 A0, A1, A2, A3, P0, P1, P2, P3, Q0, Q1, Q2, Q3;
  auto LD = [&](int kc, s16x8& a, s16x8& p, s16x8& qq) {
    int o = kc * 32;
    a  = *(const s16x8*)(Ap + o);
    p  = *(const s16x8*)(B0 + o);
    qq = *(const s16x8*)(B1 + o);
  };
  auto ST = [&](s16x8& a, s16x8& p, s16x8& qq) {
    acc0 = __builtin_amdgcn_mfma_f32_16x16x32_bf16(a, p,  acc0, 0, 0, 0);
    acc1 = __builtin_amdgcn_mfma_f32_16x16x32_bf16(a, qq, acc1, 0, 0, 0);
  };
  LD(0, A0, P0, Q0); LD(1, A1, P1, Q1); LD(2, A2, P2, Q2); LD(3, A3, P3, Q3);
#pragma unroll
  for (int kc = 0; kc < 32; kc += 4) {
    ST(A0, P0, Q0); if (kc + 4 < 32) LD(kc + 4, A0, P0, Q0);
    ST(A1, P1, Q1); if (kc + 5 < 32) LD(kc + 5, A1, P1, Q1);
    ST(A2, P2, Q2); if (kc + 6 < 32) LD(kc + 6, A2, P2, Q2);
    ST(A3, P3, Q3); if (kc + 7 < 32) LD(kc + 7, A3, P3, Q3);
  }
  int c0 = mt * 16 + lg * 4;
  int nn0 = ng * 32 + lr, nn1 = nn0 + 16;
  size_t ob0 = (size_t)(2 * (nn0 >> 5) + py) * WW + 2 * (nn0 & 31) + px;
  size_t ob1 = (size_t)(2 * (nn1 >> 5) + py) * WW + 2 * (nn1 & 31) + px;
  float* os = out + (size_t)s * NC * HH * WW;
#pragma unroll
  for (int r = 0; r < 4; ++r) {
    os[(size_t)(c0 + r) * (HH * WW) + ob0] = acc0[r] * 0.25f;
    os[(size_t)(c0 + r) * (HH * WW) + ob1] = acc1[r] * 0.25f;
  }
}

extern "C" void kernel_launch(void* const* d_in, const int* in_sizes, int n_in,
                              void* d_out, int out_size, void* d_ws, size_t ws_size,
                              hipStream_t stream) {
  const float* f    = (const float*)d_in[0];
  const float* b    = (const float*)d_in[1];
  const float* mask = (const float*)d_in[2];
  float* out  = (float*)d_out;

  // workspace layout: ~74 MB
  float* buf0 = (float*)d_ws;              // 4,194,304 f (Gt -> yiT)
  float* buf1 = buf0 + 4194304;            // 4,194,304 f (St)
  u16* bsT_hi = (u16*)(buf1 + 4194304);    // 524,288 u16 each
  u16* bsT_lo = bsT_hi + 524288;
  u16* fsT_hi = bsT_lo + 524288;
  u16* fsT_lo = fsT_hi + 524288;
  u16* Wt     = fsT_lo + 524288;           // 2,097,152 u16
  float* Q    = (float*)(Wt + 2097152);    // 4,096
  float* nrm  = Q + 4096;                  // 4,096
  float* mmv  = nrm + 4096;                // 4,096
  u16* Pb     = (u16*)(mmv + 4096);        // 16,777,216 u16 (32 MB, all 16 z)

  hipLaunchKernelGGL(prep, dim3(256), dim3(256), 0, stream, f, b, bsT_hi, bsT_lo, fsT_hi, fsT_lo, Q);
  hipLaunchKernelGGL(prep_wt, dim3(2048), dim3(256), 0, stream, b, Wt);
  hipLaunchKernelGGL(aux_nrm, dim3(4), dim3(1024), 0, stream, Q, mask, nrm, mmv);
  hipLaunchKernelGGL(gram_mfma, dim3(1024), dim3(256), 0, stream, fsT_hi, fsT_lo, bsT_hi, bsT_lo, buf0);
  hipLaunchKernelGGL(sbuildT, dim3(4, 1024, 4), dim3(256), 0, stream, buf0, nrm, buf1);
  hipLaunchKernelGGL(fuse12_softmax, dim3(1024), dim3(256), 0, stream, buf1, mmv, buf0);
  hipLaunchKernelGGL(build_p, dim3(4096), dim3(256), 0, stream, buf0, Pb);
  hipLaunchKernelGGL(deconv_gemm, dim3(1024), dim3(256), 0, stream, Pb, Wt, out);
}

// Round 7
// 157.363 us; speedup vs baseline: 1.9099x; 1.1329x over previous
//
#include <hip/hip_runtime.h>
#include <math.h>

#define NS 4
#define NC 128
#define HH 64
#define WW 64
#define LL 1024   // 32*32

typedef unsigned short u16;
typedef u16 u16x4 __attribute__((ext_vector_type(4)));
typedef short s16x8 __attribute__((ext_vector_type(8)));
typedef float f32x4 __attribute__((ext_vector_type(4)));

__device__ __forceinline__ u16 f2bf(float x) {
  unsigned u = __float_as_uint(x);
  return (u16)((u + 0x7FFFu + ((u >> 16) & 1u)) >> 16);
}
__device__ __forceinline__ float bf2f(u16 h) {
  return __uint_as_float(((unsigned)h) << 16);
}

// ---------------- prep: hi/lo bf16 operands (rows contiguous in c) + Q[s][p]=patch ssq
__global__ __launch_bounds__(256) void prep(const float* __restrict__ f,
                                            const float* __restrict__ b,
                                            u16* __restrict__ bsT_hi, u16* __restrict__ bsT_lo,
                                            u16* __restrict__ fsT_hi, u16* __restrict__ fsT_lo,
                                            float* __restrict__ Q) {
  int t = threadIdx.x;
  int idx = blockIdx.x * 256 + t;                // 65536 = 4s*1024q*16cog
  int co = (idx & 15) * 8;
  int q  = (idx >> 4) & 1023;
  int s  = idx >> 14;
  int qh = q >> 5, qw = q & 31;
  size_t g0 = ((size_t)(s * NC) * HH + 2 * qh) * WW + 2 * qw;
  u16x4 fh0, fh1, fl0, fl1, bh0, bh1, bl0, bl1;
  u16* fhv[2] = { (u16*)&fh0, (u16*)&fh1 };
  u16* flv[2] = { (u16*)&fl0, (u16*)&fl1 };
  u16* bhv[2] = { (u16*)&bh0, (u16*)&bh1 };
  u16* blv[2] = { (u16*)&bl0, (u16*)&bl1 };
  float ssq = 0.f;
#pragma unroll
  for (int e = 0; e < 8; ++e) {
    size_t off = g0 + (size_t)(co + e) * (HH * WW);
    float xf = f[off], xb = b[off];
    ssq += xb * xb;
    u16 hf = f2bf(xf); u16 lf = f2bf(xf - bf2f(hf));
    u16 hb = f2bf(xb); u16 lb = f2bf(xb - bf2f(hb));
    fhv[e >> 2][e & 3] = hf; flv[e >> 2][e & 3] = lf;
    bhv[e >> 2][e & 3] = hb; blv[e >> 2][e & 3] = lb;
  }
  size_t o = ((size_t)(s * LL) + q) * NC + co;
  *(u16x4*)(fsT_hi + o) = fh0; *(u16x4*)(fsT_hi + o + 4) = fh1;
  *(u16x4*)(fsT_lo + o) = fl0; *(u16x4*)(fsT_lo + o + 4) = fl1;
  *(u16x4*)(bsT_hi + o) = bh0; *(u16x4*)(bsT_hi + o + 4) = bh1;
  *(u16x4*)(bsT_lo + o) = bl0; *(u16x4*)(bsT_lo + o + 4) = bl1;
  __shared__ float SS[256];
  SS[t] = ssq;
  __syncthreads();
  if (t < 16) {
    float sum = 0.f;
#pragma unroll
    for (int j = 0; j < 16; ++j) sum += SS[t * 16 + j];
    Q[s * LL + ((blockIdx.x * 16 + t) & 1023)] = sum;
  }
}

// ---------------- prep: Wt[z][c][k] bf16
__global__ __launch_bounds__(256) void prep_wt(const float* __restrict__ b,
                                               u16* __restrict__ Wt) {
  int q = blockIdx.x * 256 + threadIdx.x;        // 524288 quads
  int k4 = (q & 255) * 4;
  int c  = (q >> 8) & 127;
  int z  = q >> 15;
  int s = z >> 2, cls = z & 3, py = cls >> 1, px = cls & 1;
  int kh = k4 >> 5, kw = k4 & 31;
  const float* src = b + ((size_t)(s * NC + c) * HH + 2 * kh + py) * WW + px;
  u16x4 v;
#pragma unroll
  for (int i = 0; i < 4; ++i) v[i] = f2bf(src[2 * (kw + i)]);
  *(u16x4*)(Wt + (size_t)q * 4) = v;
}

// ---------------- aux: nrm[p] (9-tap of Q + eps) and mmv[p]
__global__ __launch_bounds__(1024) void aux_nrm(const float* __restrict__ Q,
                                                const float* __restrict__ mask,
                                                float* __restrict__ nrm,
                                                float* __restrict__ mmv) {
  int s = blockIdx.x;
  int p = threadIdx.x;
  __shared__ float Ql[LL];
  __shared__ float M[LL];
  Ql[p] = Q[s * LL + p];
  int ph = p >> 5, pw = p & 31;
  M[p] = mask[s * HH * WW + (2 * ph) * WW + 2 * pw];
  __syncthreads();
  float sum2 = 1152 * 1e-4f;
  float msum = 0.f;
#pragma unroll
  for (int dh = -1; dh <= 1; ++dh)
#pragma unroll
    for (int dw = -1; dw <= 1; ++dw) {
      int h = ph + dh, w = pw + dw;
      if (h >= 0 && h < 32 && w >= 0 && w < 32) {
        sum2 += Ql[h * 32 + w];
        msum += M[h * 32 + w];
      }
    }
  nrm[s * LL + p] = sqrtf(sum2);
  mmv[s * LL + p] = msum * (1.f / 9.f);
}

// ---------------- Gt[q][p] = sum_c fs[c][q]*bs[c][p], split-bf16 MFMA,
// 4 waves/block, 4 n-tiles/wave, 2-deep prefetch over K=128
__global__ __launch_bounds__(256) void gram_mfma(const u16* __restrict__ aT_hi,
                                                 const u16* __restrict__ aT_lo,
                                                 const u16* __restrict__ bT_hi,
                                                 const u16* __restrict__ bT_lo,
                                                 float* __restrict__ G) {
  int wid = blockIdx.x * 4 + (threadIdx.x >> 6);  // 4096 = 4s * 64mt * 16ngg
  int ngg = wid & 15, mt = (wid >> 4) & 63, s = wid >> 10;
  int l = threadIdx.x & 63, lr = l & 15, lg = l >> 4;
  const u16* Ah = aT_hi + ((size_t)(s * LL) + mt * 16 + lr) * NC + lg * 8;
  const u16* Al = aT_lo + ((size_t)(s * LL) + mt * 16 + lr) * NC + lg * 8;
  size_t bbase = ((size_t)(s * LL) + ngg * 64 + lr) * NC + lg * 8;
  f32x4 acc[4] = {};
  s16x8 ah0, al0, bh0[4], bl0[4];
  s16x8 ah1, al1, bh1[4], bl1[4];
  auto LD = [&](int kc, s16x8& ah, s16x8& al, s16x8* bh, s16x8* bl) {
    int o = kc * 32;
    ah = *(const s16x8*)(Ah + o);
    al = *(const s16x8*)(Al + o);
#pragma unroll
    for (int nt = 0; nt < 4; ++nt) {
      bh[nt] = *(const s16x8*)(bT_hi + bbase + nt * 16 * NC + o);
      bl[nt] = *(const s16x8*)(bT_lo + bbase + nt * 16 * NC + o);
    }
  };
  auto ST = [&](s16x8& ah, s16x8& al, s16x8* bh, s16x8* bl) {
#pragma unroll
    for (int nt = 0; nt < 4; ++nt) {
      acc[nt] = __builtin_amdgcn_mfma_f32_16x16x32_bf16(ah, bh[nt], acc[nt], 0, 0, 0);
      acc[nt] = __builtin_amdgcn_mfma_f32_16x16x32_bf16(ah, bl[nt], acc[nt], 0, 0, 0);
      acc[nt] = __builtin_amdgcn_mfma_f32_16x16x32_bf16(al, bh[nt], acc[nt], 0, 0, 0);
    }
  };
  LD(0, ah0, al0, bh0, bl0);
  LD(1, ah1, al1, bh1, bl1);
  ST(ah0, al0, bh0, bl0);
  LD(2, ah0, al0, bh0, bl0);
  ST(ah1, al1, bh1, bl1);
  LD(3, ah1, al1, bh1, bl1);
  ST(ah0, al0, bh0, bl0);
  ST(ah1, al1, bh1, bl1);
  float* Gs = G + ((size_t)s << 20);
  int qrow = mt * 16 + lg * 4;
#pragma unroll
  for (int nt = 0; nt < 4; ++nt) {
    int p0 = ngg * 64 + nt * 16 + lr;
#pragma unroll
    for (int r = 0; r < 4; ++r)
      Gs[(size_t)(qrow + r) * LL + p0] = acc[nt][r];
  }
}

// ---------------- St[q][p] = (9-tap 2D-clipped diagonal of Gt) / nrm[p]
__global__ __launch_bounds__(256) void sbuildT(const float* __restrict__ Gt,
                                               const float* __restrict__ nrm,
                                               float* __restrict__ St) {
  int s = blockIdx.z;
  int q = blockIdx.y;
  int p = blockIdx.x * 256 + threadIdx.x;
  int qh = q >> 5, qw = q & 31, ph = p >> 5, pw = p & 31;
  const float* Gs = Gt + ((size_t)s << 20);
  float acc = 0.f;
#pragma unroll
  for (int dh = -1; dh <= 1; ++dh)
#pragma unroll
    for (int dw = -1; dw <= 1; ++dw) {
      int ph2 = ph + dh, pw2 = pw + dw, qh2 = qh + dh, qw2 = qw + dw;
      if (ph2 >= 0 && ph2 < 32 && pw2 >= 0 && pw2 < 32 &&
          qh2 >= 0 && qh2 < 32 && qw2 >= 0 && qw2 < 32)
        acc += Gs[(size_t)(qh2 * 32 + qw2) * LL + ph2 * 32 + pw2];
    }
  St[((size_t)s << 20) + (size_t)q * LL + p] = acc / nrm[s * LL + p];
}

// ---------------- fused fuse1 + fuse2 + row-softmax (one wave per output row q)
__global__ __launch_bounds__(256) void fuse12_softmax(const float* __restrict__ St,
                                                      const float* __restrict__ mmv,
                                                      float* __restrict__ yiT) {
  int g = blockIdx.x * 4 + (threadIdx.x >> 6);   // 4096 rows
  int s = g >> 10, q = g & 1023;
  int lane = threadIdx.x & 63;
  const float* Ss = St + ((size_t)s << 20);
  const float* mm = mmv + s * LL;
  int qh = q >> 5, qw = q & 31;
  int rq[3]; bool vq[3];
  if (qh > 0)      { rq[0] = q - 32;        vq[0] = true; }
  else if (qw > 0) { rq[0] = 992 + qw - 1;  vq[0] = true; }
  else             { rq[0] = 0;             vq[0] = false; }
  rq[1] = q; vq[1] = true;
  if (qh < 31)      { rq[2] = q + 32;   vq[2] = true; }
  else if (qw < 31) { rq[2] = qw + 1;   vq[2] = true; }
  else              { rq[2] = 0;        vq[2] = false; }
  float v[16];
  float mx = -1e30f;
#pragma unroll
  for (int i = 0; i < 16; ++i) {
    int p = i * 64 + lane;
    int ph = p >> 5, pw = p & 31;
    int rp[3]; bool vp[3];
    if (ph > 0)      { rp[0] = p - 32;        vp[0] = true; }
    else if (pw > 0) { rp[0] = 992 + pw - 1;  vp[0] = true; }
    else             { rp[0] = 0;             vp[0] = false; }
    rp[1] = p; vp[1] = true;
    if (ph < 31)      { rp[2] = p + 32;   vp[2] = true; }
    else if (pw < 31) { rp[2] = pw + 1;   vp[2] = true; }
    else              { rp[2] = 0;        vp[2] = false; }
    float acc = 0.f;
#pragma unroll
    for (int d2 = 0; d2 < 3; ++d2) {
      if (vq[d2] && vp[d2]) {
#pragma unroll
        for (int d1 = -1; d1 <= 1; ++d1) {
          int rr = rq[d2] + d1, cc = rp[d2] + d1;
          if ((unsigned)rr < 1024u && (unsigned)cc < 1024u)
            acc += Ss[(size_t)rr * LL + cc];
        }
      }
    }
    float val = acc * mm[p] * 10.f;
    v[i] = val;
    mx = fmaxf(mx, val);
  }
#pragma unroll
  for (int o = 32; o; o >>= 1) mx = fmaxf(mx, __shfl_xor(mx, o));
  float sum = 0.f;
#pragma unroll
  for (int i = 0; i < 16; ++i) { v[i] = __expf(v[i] - mx); sum += v[i]; }
#pragma unroll
  for (int o = 32; o; o >>= 1) sum += __shfl_xor(sum, o);
  float inv = 1.f / sum;
  float* yo = yiT + ((size_t)s << 20) + (size_t)q * LL;
#pragma unroll
  for (int i = 0; i < 16; ++i) {
    int p = i * 64 + lane;
    yo[p] = v[i] * inv * mm[p];
  }
}

// ---------------- build P (4-tap diagonal sums of yiT) as bf16; one block per
// (s, ih, 4-jw strip): 18-row LDS stage shared by 4 n x 4 cls outputs
__global__ __launch_bounds__(256) void build_p(const float* __restrict__ yiT,
                                               u16* __restrict__ Pb) {
  int bx = blockIdx.x;               // 1024 = 4s * 32ih * 8jg
  int jg = bx & 7, ih = (bx >> 3) & 31, s = bx >> 8;
  int jw0 = jg * 4;
  const float* Y = yiT + ((size_t)s << 20);
  __shared__ float R[18][1024];      // [di*6+jj][k]
  int t = threadIdx.x;
#pragma unroll
  for (int r = 0; r < 18; ++r) {
    int di = r / 6, jj = r % 6;
    int ihh = ih + di - 1, jww = jw0 + jj - 1;
    bool vld = ((unsigned)ihh < 32u) && ((unsigned)jww < 32u);
    float4 val = vld ? *(const float4*)(Y + ((size_t)(ihh * 32 + jww) << 10) + t * 4)
                     : make_float4(0.f, 0.f, 0.f, 0.f);
    *(float4*)&R[r][t * 4] = val;
  }
  __syncthreads();
  int nl = t >> 6, lane = t & 63;
  int n = ih * 32 + jw0 + nl;
#pragma unroll
  for (int kq = 0; kq < 4; ++kq) {
    int k0 = (kq * 64 + lane) * 4;
    int kh = k0 >> 5;
#pragma unroll
    for (int cls = 0; cls < 4; ++cls) {
      int py = cls >> 1, px = cls & 1;
      int sy = py ? 1 : -1, sx = px ? 1 : -1;
      const float* RA = R[6 + nl + 1];
      const float* RB = R[(1 + sy) * 6 + nl + 1];
      const float* RC = R[6 + nl + 1 + sx];
      const float* RD = R[(1 + sy) * 6 + nl + 1 + sx];
      bool mB = (unsigned)(kh + sy) < 32u;
      int ob = 32 * sy;
      u16x4 pk;
#pragma unroll
      for (int e = 0; e < 4; ++e) {
        int k = k0 + e, kw = k & 31;
        bool mC = (unsigned)(kw + sx) < 32u;
        float v = RA[k];
        if (mB) v += RB[k + ob];
        if (mC) v += RC[k + sx];
        if (mB && mC) v += RD[k + ob + sx];
        pk[e] = f2bf(v);
      }
      int zz = s * 4 + cls;
      *(u16x4*)(Pb + (((size_t)(zz * LL + n)) << 10) + k0) = pk;
    }
  }
}

// ---------------- deconv GEMM v3: wave = 32c x 64n, block = 4 waves (64c x 128n),
// grid 256 = 16z * 2cb * 8nb, depth-4 register prefetch, K=1024
#define DGLD(i, kc) { int o = (kc) * 32;                      \
    A##i##0 = *(const s16x8*)(Ap0 + o);                       \
    A##i##1 = *(const s16x8*)(Ap1 + o);                       \
    B##i##0 = *(const s16x8*)(Bp0 + o);                       \
    B##i##1 = *(const s16x8*)(Bp1 + o);                       \
    B##i##2 = *(const s16x8*)(Bp2 + o);                       \
    B##i##3 = *(const s16x8*)(Bp3 + o); }
#define DGST(i) {                                                                     \
    acc[0][0] = __builtin_amdgcn_mfma_f32_16x16x32_bf16(A##i##0, B##i##0, acc[0][0], 0, 0, 0); \
    acc[0][1] = __builtin_amdgcn_mfma_f32_16x16x32_bf16(A##i##0, B##i##1, acc[0][1], 0, 0, 0); \
    acc[0][2] = __builtin_amdgcn_mfma_f32_16x16x32_bf16(A##i##0, B##i##2, acc[0][2], 0, 0, 0); \
    acc[0][3] = __builtin_amdgcn_mfma_f32_16x16x32_bf16(A##i##0, B##i##3, acc[0][3], 0, 0, 0); \
    acc[1][0] = __builtin_amdgcn_mfma_f32_16x16x32_bf16(A##i##1, B##i##0, acc[1][0], 0, 0, 0); \
    acc[1][1] = __builtin_amdgcn_mfma_f32_16x16x32_bf16(A##i##1, B##i##1, acc[1][1], 0, 0, 0); \
    acc[1][2] = __builtin_amdgcn_mfma_f32_16x16x32_bf16(A##i##1, B##i##2, acc[1][2], 0, 0, 0); \
    acc[1][3] = __builtin_amdgcn_mfma_f32_16x16x32_bf16(A##i##1, B##i##3, acc[1][3], 0, 0, 0); }

__global__ __launch_bounds__(256, 1) void deconv_gemm(const u16* __restrict__ Pb,
                                                      const u16* __restrict__ Wt,
                                                      float* __restrict__ out) {
  int bx = blockIdx.x;               // 256 = 16z * 2cb * 8nb
  int nb = bx & 7, cb = (bx >> 3) & 1, z = bx >> 4;
  int s = z >> 2, cls = z & 3, py = cls >> 1, px = cls & 1;
  int wz = threadIdx.x >> 6;
  int wc = wz >> 1, wn = wz & 1;
  int l = threadIdx.x & 63, lr = l & 15, lg = l >> 4;
  int c0 = cb * 64 + wc * 32;
  int n0 = nb * 128 + wn * 64;
  const u16* Ap0 = Wt + ((size_t)z * NC + c0 + lr) * LL + lg * 8;
  const u16* Ap1 = Ap0 + (size_t)16 * LL;
  const u16* Bp0 = Pb + ((size_t)(z * LL + n0 + lr)) * LL + lg * 8;
  const u16* Bp1 = Bp0 + (size_t)16 * LL;
  const u16* Bp2 = Bp0 + (size_t)32 * LL;
  const u16* Bp3 = Bp0 + (size_t)48 * LL;
  f32x4 acc[2][4] = {};
  s16x8 A00, A01, B00, B01, B02, B03;
  s16x8 A10, A11, B10, B11, B12, B13;
  s16x8 A20, A21, B20, B21, B22, B23;
  s16x8 A30, A31, B30, B31, B32, B33;
  DGLD(0, 0) DGLD(1, 1) DGLD(2, 2) DGLD(3, 3)
#pragma unroll
  for (int kc = 0; kc < 32; kc += 4) {
    DGST(0) if (kc + 4 < 32) DGLD(0, kc + 4)
    DGST(1) if (kc + 5 < 32) DGLD(1, kc + 5)
    DGST(2) if (kc + 6 < 32) DGLD(2, kc + 6)
    DGST(3) if (kc + 7 < 32) DGLD(3, kc + 7)
  }
  float* os = out + (size_t)s * NC * HH * WW;
#pragma unroll
  for (int mt = 0; mt < 2; ++mt) {
    int cc = c0 + mt * 16 + lg * 4;
#pragma unroll
    for (int nt = 0; nt < 4; ++nt) {
      int nn = n0 + nt * 16 + lr;
      size_t ob = (size_t)(2 * (nn >> 5) + py) * WW + 2 * (nn & 31) + px;
#pragma unroll
      for (int r = 0; r < 4; ++r)
        os[(size_t)(cc + r) * (HH * WW) + ob] = acc[mt][nt][r] * 0.25f;
    }
  }
}

extern "C" void kernel_launch(void* const* d_in, const int* in_sizes, int n_in,
                              void* d_out, int out_size, void* d_ws, size_t ws_size,
                              hipStream_t stream) {
  const float* f    = (const float*)d_in[0];
  const float* b    = (const float*)d_in[1];
  const float* mask = (const float*)d_in[2];
  float* out  = (float*)d_out;

  // workspace layout: ~74 MB
  float* buf0 = (float*)d_ws;              // 4,194,304 f (Gt -> yiT)
  float* buf1 = buf0 + 4194304;            // 4,194,304 f (St)
  u16* bsT_hi = (u16*)(buf1 + 4194304);    // 524,288 u16 each
  u16* bsT_lo = bsT_hi + 524288;
  u16* fsT_hi = bsT_lo + 524288;
  u16* fsT_lo = fsT_hi + 524288;
  u16* Wt     = fsT_lo + 524288;           // 2,097,152 u16
  float* Q    = (float*)(Wt + 2097152);    // 4,096
  float* nrm  = Q + 4096;                  // 4,096
  float* mmv  = nrm + 4096;                // 4,096
  u16* Pb     = (u16*)(mmv + 4096);        // 16,777,216 u16 (32 MB, all 16 z)

  hipLaunchKernelGGL(prep, dim3(256), dim3(256), 0, stream, f, b, bsT_hi, bsT_lo, fsT_hi, fsT_lo, Q);
  hipLaunchKernelGGL(prep_wt, dim3(2048), dim3(256), 0, stream, b, Wt);
  hipLaunchKernelGGL(aux_nrm, dim3(4), dim3(1024), 0, stream, Q, mask, nrm, mmv);
  hipLaunchKernelGGL(gram_mfma, dim3(1024), dim3(256), 0, stream, fsT_hi, fsT_lo, bsT_hi, bsT_lo, buf0);
  hipLaunchKernelGGL(sbuildT, dim3(4, 1024, 4), dim3(256), 0, stream, buf0, nrm, buf1);
  hipLaunchKernelGGL(fuse12_softmax, dim3(1024), dim3(256), 0, stream, buf1, mmv, buf0);
  hipLaunchKernelGGL(build_p, dim3(1024), dim3(256), 0, stream, buf0, Pb);
  hipLaunchKernelGGL(deconv_gemm, dim3(256), dim3(256), 0, stream, Pb, Wt, out);
}

// Round 8
// 134.326 us; speedup vs baseline: 2.2375x; 1.1715x over previous
//
#include <hip/hip_runtime.h>
#include <math.h>

#define NS 4
#define NC 128
#define HH 64
#define WW 64
#define LL 1024   // 32*32

typedef unsigned short u16;
typedef u16 u16x4 __attribute__((ext_vector_type(4)));
typedef short s16x8 __attribute__((ext_vector_type(8)));
typedef float f32x4 __attribute__((ext_vector_type(4)));

__device__ __forceinline__ u16 f2bf(float x) {
  unsigned u = __float_as_uint(x);
  return (u16)((u + 0x7FFFu + ((u >> 16) & 1u)) >> 16);
}
__device__ __forceinline__ float bf2f(u16 h) {
  return __uint_as_float(((unsigned)h) << 16);
}

// ---------------- prep: hi/lo bf16 operands (rows contiguous in c) + Q[s][p]=patch ssq
__global__ __launch_bounds__(256) void prep(const float* __restrict__ f,
                                            const float* __restrict__ b,
                                            u16* __restrict__ bsT_hi, u16* __restrict__ bsT_lo,
                                            u16* __restrict__ fsT_hi, u16* __restrict__ fsT_lo,
                                            float* __restrict__ Q) {
  int t = threadIdx.x;
  int idx = blockIdx.x * 256 + t;                // 65536 = 4s*1024q*16cog
  int co = (idx & 15) * 8;
  int q  = (idx >> 4) & 1023;
  int s  = idx >> 14;
  int qh = q >> 5, qw = q & 31;
  size_t g0 = ((size_t)(s * NC) * HH + 2 * qh) * WW + 2 * qw;
  u16x4 fh0, fh1, fl0, fl1, bh0, bh1, bl0, bl1;
  u16* fhv[2] = { (u16*)&fh0, (u16*)&fh1 };
  u16* flv[2] = { (u16*)&fl0, (u16*)&fl1 };
  u16* bhv[2] = { (u16*)&bh0, (u16*)&bh1 };
  u16* blv[2] = { (u16*)&bl0, (u16*)&bl1 };
  float ssq = 0.f;
#pragma unroll
  for (int e = 0; e < 8; ++e) {
    size_t off = g0 + (size_t)(co + e) * (HH * WW);
    float xf = f[off], xb = b[off];
    ssq += xb * xb;
    u16 hf = f2bf(xf); u16 lf = f2bf(xf - bf2f(hf));
    u16 hb = f2bf(xb); u16 lb = f2bf(xb - bf2f(hb));
    fhv[e >> 2][e & 3] = hf; flv[e >> 2][e & 3] = lf;
    bhv[e >> 2][e & 3] = hb; blv[e >> 2][e & 3] = lb;
  }
  size_t o = ((size_t)(s * LL) + q) * NC + co;
  *(u16x4*)(fsT_hi + o) = fh0; *(u16x4*)(fsT_hi + o + 4) = fh1;
  *(u16x4*)(fsT_lo + o) = fl0; *(u16x4*)(fsT_lo + o + 4) = fl1;
  *(u16x4*)(bsT_hi + o) = bh0; *(u16x4*)(bsT_hi + o + 4) = bh1;
  *(u16x4*)(bsT_lo + o) = bl0; *(u16x4*)(bsT_lo + o + 4) = bl1;
  __shared__ float SS[256];
  SS[t] = ssq;
  __syncthreads();
  if (t < 16) {
    float sum = 0.f;
#pragma unroll
    for (int j = 0; j < 16; ++j) sum += SS[t * 16 + j];
    Q[s * LL + ((blockIdx.x * 16 + t) & 1023)] = sum;
  }
}

// ---------------- prep: Wt[z][c][k] bf16
__global__ __launch_bounds__(256) void prep_wt(const float* __restrict__ b,
                                               u16* __restrict__ Wt) {
  int q = blockIdx.x * 256 + threadIdx.x;        // 524288 quads
  int k4 = (q & 255) * 4;
  int c  = (q >> 8) & 127;
  int z  = q >> 15;
  int s = z >> 2, cls = z & 3, py = cls >> 1, px = cls & 1;
  int kh = k4 >> 5, kw = k4 & 31;
  const float* src = b + ((size_t)(s * NC + c) * HH + 2 * kh + py) * WW + px;
  u16x4 v;
#pragma unroll
  for (int i = 0; i < 4; ++i) v[i] = f2bf(src[2 * (kw + i)]);
  *(u16x4*)(Wt + (size_t)q * 4) = v;
}

// ---------------- aux: nrm[p] (9-tap of Q + eps) and mmv[p]
__global__ __launch_bounds__(1024) void aux_nrm(const float* __restrict__ Q,
                                                const float* __restrict__ mask,
                                                float* __restrict__ nrm,
                                                float* __restrict__ mmv) {
  int s = blockIdx.x;
  int p = threadIdx.x;
  __shared__ float Ql[LL];
  __shared__ float M[LL];
  Ql[p] = Q[s * LL + p];
  int ph = p >> 5, pw = p & 31;
  M[p] = mask[s * HH * WW + (2 * ph) * WW + 2 * pw];
  __syncthreads();
  float sum2 = 1152 * 1e-4f;
  float msum = 0.f;
#pragma unroll
  for (int dh = -1; dh <= 1; ++dh)
#pragma unroll
    for (int dw = -1; dw <= 1; ++dw) {
      int h = ph + dh, w = pw + dw;
      if (h >= 0 && h < 32 && w >= 0 && w < 32) {
        sum2 += Ql[h * 32 + w];
        msum += M[h * 32 + w];
      }
    }
  nrm[s * LL + p] = sqrtf(sum2);
  mmv[s * LL + p] = msum * (1.f / 9.f);
}

// ---------------- Gt[q][p] = sum_c fs[c][q]*bs[c][p], split-bf16 MFMA,
// 4 waves/block, 4 n-tiles/wave, 2-deep prefetch over K=128
__global__ __launch_bounds__(256) void gram_mfma(const u16* __restrict__ aT_hi,
                                                 const u16* __restrict__ aT_lo,
                                                 const u16* __restrict__ bT_hi,
                                                 const u16* __restrict__ bT_lo,
                                                 float* __restrict__ G) {
  int wid = blockIdx.x * 4 + (threadIdx.x >> 6);  // 4096 = 4s * 64mt * 16ngg
  int ngg = wid & 15, mt = (wid >> 4) & 63, s = wid >> 10;
  int l = threadIdx.x & 63, lr = l & 15, lg = l >> 4;
  const u16* Ah = aT_hi + ((size_t)(s * LL) + mt * 16 + lr) * NC + lg * 8;
  const u16* Al = aT_lo + ((size_t)(s * LL) + mt * 16 + lr) * NC + lg * 8;
  size_t bbase = ((size_t)(s * LL) + ngg * 64 + lr) * NC + lg * 8;
  f32x4 acc[4] = {};
  s16x8 ah0, al0, bh0[4], bl0[4];
  s16x8 ah1, al1, bh1[4], bl1[4];
  auto LD = [&](int kc, s16x8& ah, s16x8& al, s16x8* bh, s16x8* bl) {
    int o = kc * 32;
    ah = *(const s16x8*)(Ah + o);
    al = *(const s16x8*)(Al + o);
#pragma unroll
    for (int nt = 0; nt < 4; ++nt) {
      bh[nt] = *(const s16x8*)(bT_hi + bbase + nt * 16 * NC + o);
      bl[nt] = *(const s16x8*)(bT_lo + bbase + nt * 16 * NC + o);
    }
  };
  auto ST = [&](s16x8& ah, s16x8& al, s16x8* bh, s16x8* bl) {
#pragma unroll
    for (int nt = 0; nt < 4; ++nt) {
      acc[nt] = __builtin_amdgcn_mfma_f32_16x16x32_bf16(ah, bh[nt], acc[nt], 0, 0, 0);
      acc[nt] = __builtin_amdgcn_mfma_f32_16x16x32_bf16(ah, bl[nt], acc[nt], 0, 0, 0);
      acc[nt] = __builtin_amdgcn_mfma_f32_16x16x32_bf16(al, bh[nt], acc[nt], 0, 0, 0);
    }
  };
  LD(0, ah0, al0, bh0, bl0);
  LD(1, ah1, al1, bh1, bl1);
  ST(ah0, al0, bh0, bl0);
  LD(2, ah0, al0, bh0, bl0);
  ST(ah1, al1, bh1, bl1);
  LD(3, ah1, al1, bh1, bl1);
  ST(ah0, al0, bh0, bl0);
  ST(ah1, al1, bh1, bl1);
  float* Gs = G + ((size_t)s << 20);
  int qrow = mt * 16 + lg * 4;
#pragma unroll
  for (int nt = 0; nt < 4; ++nt) {
    int p0 = ngg * 64 + nt * 16 + lr;
#pragma unroll
    for (int r = 0; r < 4; ++r)
      Gs[(size_t)(qrow + r) * LL + p0] = acc[nt][r];
  }
}

// ---------------- sbuildT v2: LDS row-staged. One block per (s,q).
// St[q][p] = (sum of 9 diag taps of Gt, 2D-clipped) / nrm[p]
__global__ __launch_bounds__(256) void sbuildT(const float* __restrict__ Gt,
                                               const float* __restrict__ nrm,
                                               float* __restrict__ St) {
  int g = blockIdx.x;              // 4096 = s*1024 + q
  int s = g >> 10, q = g & 1023;
  int t = threadIdx.x;
  int qh = q >> 5, qw = q & 31;
  __shared__ float L[9][1024];     // 36 KB
  const float* Gs = Gt + ((size_t)s << 20);
  // stage: slot = (dh+1)*3 + (dw+1); zero-fill invalid q-side taps
#pragma unroll
  for (int slot = 0; slot < 9; ++slot) {
    int dh = slot / 3 - 1, dw = slot % 3 - 1;
    int qh2 = qh + dh, qw2 = qw + dw;
    bool ok = ((unsigned)qh2 < 32u) && ((unsigned)qw2 < 32u);
    float4 val = ok ? *(const float4*)(Gs + ((size_t)(qh2 * 32 + qw2) << 10) + t * 4)
                    : make_float4(0.f, 0.f, 0.f, 0.f);
    *(float4*)&L[slot][t * 4] = val;
  }
  __syncthreads();
  const float* nr = nrm + s * LL;
  float* So = St + ((size_t)s << 20) + (size_t)q * LL;
#pragma unroll
  for (int ii = 0; ii < 4; ++ii) {
    int p = ii * 256 + t;
    int ph = p >> 5, pw = p & 31;
    float acc = 0.f;
#pragma unroll
    for (int dh = -1; dh <= 1; ++dh)
#pragma unroll
      for (int dw = -1; dw <= 1; ++dw) {
        int ph2 = ph + dh, pw2 = pw + dw;
        if ((unsigned)ph2 < 32u && (unsigned)pw2 < 32u)
          acc += L[(dh + 1) * 3 + (dw + 1)][p + dh * 32 + dw];
      }
    So[p] = acc / nr[p];
  }
}

// ---------------- fuse12_softmax v2: LDS row-staged. One block per (s,q).
// F2t[q][p] = sum_{d2,d1} St[Rq(d2)+d1][Rp(d2)+d1]; then softmax over p.
__global__ __launch_bounds__(256) void fuse12_softmax(const float* __restrict__ St,
                                                      const float* __restrict__ mmv,
                                                      float* __restrict__ yiT) {
  int g = blockIdx.x;              // 4096 = s*1024 + q
  int s = g >> 10, q = g & 1023;
  int t = threadIdx.x;
  int lane = t & 63, wid = t >> 6;
  __shared__ float L[9][1024];     // 36 KB
  __shared__ float red[8];
  const float* Ss = St + ((size_t)s << 20);
  const float* mm = mmv + s * LL;
  int qh = q >> 5, qw = q & 31;
  int rq[3]; bool vq[3];
  if (qh > 0)      { rq[0] = q - 32;        vq[0] = true; }
  else if (qw > 0) { rq[0] = 992 + qw - 1;  vq[0] = true; }
  else             { rq[0] = 0;             vq[0] = false; }
  rq[1] = q; vq[1] = true;
  if (qh < 31)      { rq[2] = q + 32;   vq[2] = true; }
  else if (qw < 31) { rq[2] = qw + 1;   vq[2] = true; }
  else              { rq[2] = 0;        vq[2] = false; }
  // stage: slot = d2*3 + (d1+1); zero-fill invalid q-side taps
#pragma unroll
  for (int slot = 0; slot < 9; ++slot) {
    int d2 = slot / 3, d1 = slot % 3 - 1;
    int row = rq[d2] + d1;
    bool ok = vq[d2] && ((unsigned)row < 1024u);
    float4 val = ok ? *(const float4*)(Ss + ((size_t)row << 10) + t * 4)
                    : make_float4(0.f, 0.f, 0.f, 0.f);
    *(float4*)&L[slot][t * 4] = val;
  }
  __syncthreads();
  float v[4], mval[4];
  float mx = -1e30f;
#pragma unroll
  for (int ii = 0; ii < 4; ++ii) {
    int p = ii * 256 + t;
    int ph = p >> 5, pw = p & 31;
    int rp[3]; bool vp[3];
    if (ph > 0)      { rp[0] = p - 32;        vp[0] = true; }
    else if (pw > 0) { rp[0] = 992 + pw - 1;  vp[0] = true; }
    else             { rp[0] = 0;             vp[0] = false; }
    rp[1] = p; vp[1] = true;
    if (ph < 31)      { rp[2] = p + 32;   vp[2] = true; }
    else if (pw < 31) { rp[2] = pw + 1;   vp[2] = true; }
    else              { rp[2] = 0;        vp[2] = false; }
    float acc = 0.f;
#pragma unroll
    for (int d2 = 0; d2 < 3; ++d2) {
      if (vp[d2]) {
#pragma unroll
        for (int d1 = -1; d1 <= 1; ++d1) {
          int cc = rp[d2] + d1;
          if ((unsigned)cc < 1024u)
            acc += L[d2 * 3 + d1 + 1][cc];
        }
      }
    }
    mval[ii] = mm[p];
    float val = acc * mval[ii] * 10.f;
    v[ii] = val;
    mx = fmaxf(mx, val);
  }
#pragma unroll
  for (int o = 32; o; o >>= 1) mx = fmaxf(mx, __shfl_xor(mx, o));
  if (lane == 0) red[wid] = mx;
  __syncthreads();
  mx = fmaxf(fmaxf(red[0], red[1]), fmaxf(red[2], red[3]));
  float sum = 0.f;
#pragma unroll
  for (int ii = 0; ii < 4; ++ii) { v[ii] = __expf(v[ii] - mx); sum += v[ii]; }
#pragma unroll
  for (int o = 32; o; o >>= 1) sum += __shfl_xor(sum, o);
  if (lane == 0) red[4 + wid] = sum;
  __syncthreads();
  float tot = (red[4] + red[5]) + (red[6] + red[7]);
  float inv = 1.f / tot;
  float* yo = yiT + ((size_t)s << 20) + (size_t)q * LL;
#pragma unroll
  for (int ii = 0; ii < 4; ++ii) {
    int p = ii * 256 + t;
    yo[p] = v[ii] * inv * mval[ii];
  }
}

// ---------------- build P (4-tap diagonal sums of yiT) as bf16; one block per
// (s, ih, 4-jw strip): 18-row LDS stage shared by 4 n x 4 cls outputs
__global__ __launch_bounds__(256) void build_p(const float* __restrict__ yiT,
                                               u16* __restrict__ Pb) {
  int bx = blockIdx.x;               // 1024 = 4s * 32ih * 8jg
  int jg = bx & 7, ih = (bx >> 3) & 31, s = bx >> 8;
  int jw0 = jg * 4;
  const float* Y = yiT + ((size_t)s << 20);
  __shared__ float R[18][1024];      // [di*6+jj][k]
  int t = threadIdx.x;
#pragma unroll
  for (int r = 0; r < 18; ++r) {
    int di = r / 6, jj = r % 6;
    int ihh = ih + di - 1, jww = jw0 + jj - 1;
    bool vld = ((unsigned)ihh < 32u) && ((unsigned)jww < 32u);
    float4 val = vld ? *(const float4*)(Y + ((size_t)(ihh * 32 + jww) << 10) + t * 4)
                     : make_float4(0.f, 0.f, 0.f, 0.f);
    *(float4*)&R[r][t * 4] = val;
  }
  __syncthreads();
  int nl = t >> 6, lane = t & 63;
  int n = ih * 32 + jw0 + nl;
#pragma unroll
  for (int kq = 0; kq < 4; ++kq) {
    int k0 = (kq * 64 + lane) * 4;
    int kh = k0 >> 5;
#pragma unroll
    for (int cls = 0; cls < 4; ++cls) {
      int py = cls >> 1, px = cls & 1;
      int sy = py ? 1 : -1, sx = px ? 1 : -1;
      const float* RA = R[6 + nl + 1];
      const float* RB = R[(1 + sy) * 6 + nl + 1];
      const float* RC = R[6 + nl + 1 + sx];
      const float* RD = R[(1 + sy) * 6 + nl + 1 + sx];
      bool mB = (unsigned)(kh + sy) < 32u;
      int ob = 32 * sy;
      u16x4 pk;
#pragma unroll
      for (int e = 0; e < 4; ++e) {
        int k = k0 + e, kw = k & 31;
        bool mC = (unsigned)(kw + sx) < 32u;
        float v = RA[k];
        if (mB) v += RB[k + ob];
        if (mC) v += RC[k + sx];
        if (mB && mC) v += RD[k + ob + sx];
        pk[e] = f2bf(v);
      }
      int zz = s * 4 + cls;
      *(u16x4*)(Pb + (((size_t)(zz * LL + n)) << 10) + k0) = pk;
    }
  }
}

// ---------------- deconv GEMM v3: wave = 32c x 64n, block = 4 waves (64c x 128n),
// grid 256 = 16z * 2cb * 8nb, depth-4 register prefetch, K=1024
#define DGLD(i, kc) { int o = (kc) * 32;                      \
    A##i##0 = *(const s16x8*)(Ap0 + o);                       \
    A##i##1 = *(const s16x8*)(Ap1 + o);                       \
    B##i##0 = *(const s16x8*)(Bp0 + o);                       \
    B##i##1 = *(const s16x8*)(Bp1 + o);                       \
    B##i##2 = *(const s16x8*)(Bp2 + o);                       \
    B##i##3 = *(const s16x8*)(Bp3 + o); }
#define DGST(i) {                                                                     \
    acc[0][0] = __builtin_amdgcn_mfma_f32_16x16x32_bf16(A##i##0, B##i##0, acc[0][0], 0, 0, 0); \
    acc[0][1] = __builtin_amdgcn_mfma_f32_16x16x32_bf16(A##i##0, B##i##1, acc[0][1], 0, 0, 0); \
    acc[0][2] = __builtin_amdgcn_mfma_f32_16x16x32_bf16(A##i##0, B##i##2, acc[0][2], 0, 0, 0); \
    acc[0][3] = __builtin_amdgcn_mfma_f32_16x16x32_bf16(A##i##0, B##i##3, acc[0][3], 0, 0, 0); \
    acc[1][0] = __builtin_amdgcn_mfma_f32_16x16x32_bf16(A##i##1, B##i##0, acc[1][0], 0, 0, 0); \
    acc[1][1] = __builtin_amdgcn_mfma_f32_16x16x32_bf16(A##i##1, B##i##1, acc[1][1], 0, 0, 0); \
    acc[1][2] = __builtin_amdgcn_mfma_f32_16x16x32_bf16(A##i##1, B##i##2, acc[1][2], 0, 0, 0); \
    acc[1][3] = __builtin_amdgcn_mfma_f32_16x16x32_bf16(A##i##1, B##i##3, acc[1][3], 0, 0, 0); }

__global__ __launch_bounds__(256, 1) void deconv_gemm(const u16* __restrict__ Pb,
                                                      const u16* __restrict__ Wt,
                                                      float* __restrict__ out) {
  int bx = blockIdx.x;               // 256 = 16z * 2cb * 8nb
  int nb = bx & 7, cb = (bx >> 3) & 1, z = bx >> 4;
  int s = z >> 2, cls = z & 3, py = cls >> 1, px = cls & 1;
  int wz = threadIdx.x >> 6;
  int wc = wz >> 1, wn = wz & 1;
  int l = threadIdx.x & 63, lr = l & 15, lg = l >> 4;
  int c0 = cb * 64 + wc * 32;
  int n0 = nb * 128 + wn * 64;
  const u16* Ap0 = Wt + ((size_t)z * NC + c0 + lr) * LL + lg * 8;
  const u16* Ap1 = Ap0 + (size_t)16 * LL;
  const u16* Bp0 = Pb + ((size_t)(z * LL + n0 + lr)) * LL + lg * 8;
  const u16* Bp1 = Bp0 + (size_t)16 * LL;
  const u16* Bp2 = Bp0 + (size_t)32 * LL;
  const u16* Bp3 = Bp0 + (size_t)48 * LL;
  f32x4 acc[2][4] = {};
  s16x8 A00, A01, B00, B01, B02, B03;
  s16x8 A10, A11, B10, B11, B12, B13;
  s16x8 A20, A21, B20, B21, B22, B23;
  s16x8 A30, A31, B30, B31, B32, B33;
  DGLD(0, 0) DGLD(1, 1) DGLD(2, 2) DGLD(3, 3)
#pragma unroll
  for (int kc = 0; kc < 32; kc += 4) {
    DGST(0) if (kc + 4 < 32) DGLD(0, kc + 4)
    DGST(1) if (kc + 5 < 32) DGLD(1, kc + 5)
    DGST(2) if (kc + 6 < 32) DGLD(2, kc + 6)
    DGST(3) if (kc + 7 < 32) DGLD(3, kc + 7)
  }
  float* os = out + (size_t)s * NC * HH * WW;
#pragma unroll
  for (int mt = 0; mt < 2; ++mt) {
    int cc = c0 + mt * 16 + lg * 4;
#pragma unroll
    for (int nt = 0; nt < 4; ++nt) {
      int nn = n0 + nt * 16 + lr;
      size_t ob = (size_t)(2 * (nn >> 5) + py) * WW + 2 * (nn & 31) + px;
#pragma unroll
      for (int r = 0; r < 4; ++r)
        os[(size_t)(cc + r) * (HH * WW) + ob] = acc[mt][nt][r] * 0.25f;
    }
  }
}

extern "C" void kernel_launch(void* const* d_in, const int* in_sizes, int n_in,
                              void* d_out, int out_size, void* d_ws, size_t ws_size,
                              hipStream_t stream) {
  const float* f    = (const float*)d_in[0];
  const float* b    = (const float*)d_in[1];
  const float* mask = (const float*)d_in[2];
  float* out  = (float*)d_out;

  // workspace layout: ~74 MB
  float* buf0 = (float*)d_ws;              // 4,194,304 f (Gt -> yiT)
  float* buf1 = buf0 + 4194304;            // 4,194,304 f (St)
  u16* bsT_hi = (u16*)(buf1 + 4194304);    // 524,288 u16 each
  u16* bsT_lo = bsT_hi + 524288;
  u16* fsT_hi = bsT_lo + 524288;
  u16* fsT_lo = fsT_hi + 524288;
  u16* Wt     = fsT_lo + 524288;           // 2,097,152 u16
  float* Q    = (float*)(Wt + 2097152);    // 4,096
  float* nrm  = Q + 4096;                  // 4,096
  float* mmv  = nrm + 4096;                // 4,096
  u16* Pb     = (u16*)(mmv + 4096);        // 16,777,216 u16 (32 MB, all 16 z)

  hipLaunchKernelGGL(prep, dim3(256), dim3(256), 0, stream, f, b, bsT_hi, bsT_lo, fsT_hi, fsT_lo, Q);
  hipLaunchKernelGGL(prep_wt, dim3(2048), dim3(256), 0, stream, b, Wt);
  hipLaunchKernelGGL(aux_nrm, dim3(4), dim3(1024), 0, stream, Q, mask, nrm, mmv);
  hipLaunchKernelGGL(gram_mfma, dim3(1024), dim3(256), 0, stream, fsT_hi, fsT_lo, bsT_hi, bsT_lo, buf0);
  hipLaunchKernelGGL(sbuildT, dim3(4096), dim3(256), 0, stream, buf0, nrm, buf1);
  hipLaunchKernelGGL(fuse12_softmax, dim3(4096), dim3(256), 0, stream, buf1, mmv, buf0);
  hipLaunchKernelGGL(build_p, dim3(1024), dim3(256), 0, stream, buf0, Pb);
  hipLaunchKernelGGL(deconv_gemm, dim3(256), dim3(256), 0, stream, Pb, Wt, out);
}